// Round 1
// baseline (3852683.594 us; speedup 1.0000x reference)
//
#include <hip/hip_runtime.h>
#include <cstddef>

// ---------------- constants ----------------
// B=8, S=1024, T=256, E=256, H=512, Senc=256
// ws layout (float words)
constexpr int OXB0 = 0;                         // (8, 1026, 256) padded ch-last embed(src)
constexpr int OXB1 = OXB0 + 8 * 1026 * 256;     // (8, 514, 256) after conv1+pool
constexpr int OXB2 = OXB1 + 8 * 514 * 256;      // (8, 258, 512) after conv2+pool
constexpr int OENC = OXB2 + 8 * 258 * 512;      // (8, 256, 512) enc
constexpr int OWR1 = OENC + 8 * 256 * 512;      // 768x256   conv1 W^T
constexpr int OWR2 = OWR1 + 768 * 256;          // 768x512   conv2 W^T
constexpr int OWR3 = OWR2 + 768 * 512;          // 1536x512  conv3 W^T
constexpr int OWR0 = OWR3 + 1536 * 512;         // 256x2048  wih0^T
constexpr int OTGT = OWR0 + 256 * 2048;         // 2048x256  embed(tgt), row = t*8+b
constexpr int OXG0 = OTGT + 2048 * 256;         // 2048x2048 xg0 = emb@wih0^T + biases
constexpr int OH0S = OXG0 + 2048 * 2048;        // 257*4096  h0 sequence [t][b][512]
constexpr int OH1S = OH0S + 257 * 4096;         // 257*4096  h1 sequence (dec = t>=1)
constexpr int OCTX = OH1S + 257 * 4096;         // 8*512 ctx per batch
constexpr int OFLG = OCTX + 8 * 512;            // 514 ints: flag0[257], flag1[257]

#define ALOADR(p)   __hip_atomic_load((p), __ATOMIC_RELAXED, __HIP_MEMORY_SCOPE_AGENT)
#define ALOADACQ(p) __hip_atomic_load((p), __ATOMIC_ACQUIRE, __HIP_MEMORY_SCOPE_AGENT)
#define ASTORER(p, v) __hip_atomic_store((p), (v), __ATOMIC_RELAXED, __HIP_MEMORY_SCOPE_AGENT)

__device__ __forceinline__ void axpy4(float4& acc, float a, const float4& b) {
    acc.x += a * b.x; acc.y += a * b.y; acc.z += a * b.z; acc.w += a * b.w;
}
__device__ __forceinline__ float hsum4(const float4& a) { return a.x + a.y + a.z + a.w; }
__device__ __forceinline__ float4 relu4(float4 v, const float4& bv) {
    v.x = fmaxf(v.x + bv.x, 0.f); v.y = fmaxf(v.y + bv.y, 0.f);
    v.z = fmaxf(v.z + bv.z, 0.f); v.w = fmaxf(v.w + bv.w, 0.f); return v;
}
__device__ __forceinline__ float4 max4(const float4& a, const float4& b) {
    float4 r; r.x = fmaxf(a.x, b.x); r.y = fmaxf(a.y, b.y);
    r.z = fmaxf(a.z, b.z); r.w = fmaxf(a.w, b.w); return r;
}
__device__ __forceinline__ float sigmf(float x) { return 1.f / (1.f + expf(-x)); }

// ---------------- init: zero flags, h0[0], h1[0], pad-edge rows ----------------
__global__ void init_kernel(float* __restrict__ ws, int* __restrict__ flags) {
    int idx = blockIdx.x * 256 + threadIdx.x;
    if (idx < 4096) {
        ws[OH0S + idx] = 0.f;
        ws[OH1S + idx] = 0.f;
    } else if (idx < 8192) {
        // xbuf1 edge rows (b, rows {0,513}, 256 ch)
        int j = idx - 4096; int b = j >> 9; int rr = (j >> 8) & 1; int c = j & 255;
        ws[OXB1 + b * 131584 + (rr ? 513 : 0) * 256 + c] = 0.f;
    } else if (idx < 16384) {
        // xbuf2 edge rows (b, rows {0,257}, 512 ch)
        int j = idx - 8192; int b = j >> 10; int rr = (j >> 9) & 1; int c = j & 511;
        ws[OXB2 + b * 132096 + (rr ? 257 : 0) * 512 + c] = 0.f;
    } else if (idx < 16384 + 514) {
        flags[idx - 16384] = 0;
    }
}

// ---------------- embedding gathers ----------------
__global__ void embed_src_kernel(const int* __restrict__ src, const float* __restrict__ emb,
                                 float* __restrict__ xb0) {
    int fi = blockIdx.x * 256 + threadIdx.x;          // float4 index, total 8*1026*64
    int e4 = fi & 63;
    int r = fi >> 6;                                  // 0 .. 8*1026-1
    int b = r / 1026;
    int p = r - b * 1026;
    float4 v = make_float4(0.f, 0.f, 0.f, 0.f);
    if (p > 0 && p < 1025) {
        int row = src[b * 1024 + (p - 1)];
        v = *(const float4*)(emb + row * 256 + e4 * 4);
    }
    *(float4*)(xb0 + (size_t)fi * 4) = v;
}

__global__ void gather_tgt_kernel(const int* __restrict__ tgt, const float* __restrict__ emb,
                                  float* __restrict__ et) {
    int fi = blockIdx.x * 256 + threadIdx.x;          // total 2048*64
    int e4 = fi & 63;
    int r = fi >> 6;                                  // m = t*8 + b
    int t = r >> 3, b = r & 7;
    int row = tgt[b * 256 + t];
    *(float4*)(et + (size_t)fi * 4) = *(const float4*)(emb + row * 256 + e4 * 4);
}

// ---------------- weight transposes ----------------
// wr[(dk*Cin+ci)*Cout + co] = w[co*Cin*3 + ci*3 + dk]
__global__ void tr_conv_kernel(const float* __restrict__ w, float* __restrict__ wr,
                               int Cout, int Cin) {
    int idx = blockIdx.x * 256 + threadIdx.x;
    int co = idx / (Cin * 3);
    int rem = idx - co * Cin * 3;
    int ci = rem / 3;
    int dk = rem - ci * 3;
    wr[(dk * Cin + ci) * Cout + co] = w[idx];
}
// wr[k*N + n] = w[n*K + k]
__global__ void tr_mat_kernel(const float* __restrict__ w, float* __restrict__ wr,
                              int N, int K) {
    int idx = blockIdx.x * 256 + threadIdx.x;
    int n = idx / K;
    int k = idx - n * K;
    wr[k * N + n] = w[idx];
}

// ---------------- generic tiled GEMM: C[m][n] = sum_k A[b][m*RS + k] * Bw[k*N + n] ----------------
// mode 0: out[m*N+n] = v + bias[n] + bias2[n]                      (xg0)
// mode 1: relu(v+bias), maxpool pairs, write padded ch-last buffer (conv1/2)
// mode 2: relu(v+bias), write dense ch-last                        (conv3 -> enc)
__launch_bounds__(256)
__global__ void gemm_kernel(const float* __restrict__ A, int aBS, int RS, int K,
                            const float* __restrict__ Bw, int N,
                            const float* __restrict__ bias, const float* __restrict__ bias2,
                            float* __restrict__ out, int oBS, int mode) {
    __shared__ float As[32 * 68];   // [kk][row], stride 68
    __shared__ float Bs[32 * 64];   // [kk][n]
    const int tid = threadIdx.x;
    const int tl = tid & 15, tco = tid >> 4;
    const int m0 = blockIdx.x * 64, n0 = blockIdx.y * 64;
    const int b = blockIdx.z;
    const float* Ab = A + (size_t)b * aBS;
    float4 acc0 = make_float4(0, 0, 0, 0), acc1 = acc0, acc2 = acc0, acc3 = acc0;

    for (int k0 = 0; k0 < K; k0 += 32) {
#pragma unroll
        for (int p = 0; p < 2; ++p) {
            int f = p * 256 + tid;           // 0..511
            int row = f >> 3, j4 = f & 7;
            float4 av = *(const float4*)(Ab + (size_t)(m0 + row) * RS + k0 + j4 * 4);
            int kb = j4 * 4;
            As[(kb + 0) * 68 + row] = av.x;
            As[(kb + 1) * 68 + row] = av.y;
            As[(kb + 2) * 68 + row] = av.z;
            As[(kb + 3) * 68 + row] = av.w;
        }
#pragma unroll
        for (int p = 0; p < 2; ++p) {
            int f = p * 256 + tid;
            int kk = f >> 4, j4 = f & 15;
            *(float4*)(&Bs[kk * 64 + j4 * 4]) =
                *(const float4*)(Bw + (size_t)(k0 + kk) * N + n0 + j4 * 4);
        }
        __syncthreads();
#pragma unroll
        for (int kk = 0; kk < 32; ++kk) {
            float4 a4 = *(const float4*)(&As[kk * 68 + tl * 4]);
            float4 b4 = *(const float4*)(&Bs[kk * 64 + tco * 4]);
            axpy4(acc0, a4.x, b4);
            axpy4(acc1, a4.y, b4);
            axpy4(acc2, a4.z, b4);
            axpy4(acc3, a4.w, b4);
        }
        __syncthreads();
    }

    int nb = n0 + tco * 4;
    float4 bv;
    bv.x = bias[nb + 0]; bv.y = bias[nb + 1]; bv.z = bias[nb + 2]; bv.w = bias[nb + 3];
    if (bias2) { bv.x += bias2[nb + 0]; bv.y += bias2[nb + 1]; bv.z += bias2[nb + 2]; bv.w += bias2[nb + 3]; }

    if (mode == 0) {
        float4 v0 = acc0, v1 = acc1, v2 = acc2, v3 = acc3;
        v0.x += bv.x; v0.y += bv.y; v0.z += bv.z; v0.w += bv.w;
        v1.x += bv.x; v1.y += bv.y; v1.z += bv.z; v1.w += bv.w;
        v2.x += bv.x; v2.y += bv.y; v2.z += bv.z; v2.w += bv.w;
        v3.x += bv.x; v3.y += bv.y; v3.z += bv.z; v3.w += bv.w;
        int mr = m0 + tl * 4;
        *(float4*)(out + (size_t)(mr + 0) * N + nb) = v0;
        *(float4*)(out + (size_t)(mr + 1) * N + nb) = v1;
        *(float4*)(out + (size_t)(mr + 2) * N + nb) = v2;
        *(float4*)(out + (size_t)(mr + 3) * N + nb) = v3;
    } else if (mode == 1) {
        float4 v0 = relu4(acc0, bv), v1 = relu4(acc1, bv), v2 = relu4(acc2, bv), v3 = relu4(acc3, bv);
        float4 p0 = max4(v0, v1), p1 = max4(v2, v3);
        int lout = (m0 + tl * 4) >> 1;
        float* ob = out + (size_t)b * oBS + (size_t)(1 + lout) * N + nb;
        *(float4*)ob = p0;
        *(float4*)(ob + N) = p1;
    } else {
        float4 v0 = relu4(acc0, bv), v1 = relu4(acc1, bv), v2 = relu4(acc2, bv), v3 = relu4(acc3, bv);
        int mr = m0 + tl * 4;
        float* ob = out + (size_t)b * oBS + (size_t)mr * N + nb;
        *(float4*)(ob + 0 * N) = v0;
        *(float4*)(ob + 1 * N) = v1;
        *(float4*)(ob + 2 * N) = v2;
        *(float4*)(ob + 3 * N) = v3;
    }
}

// ---------------- persistent 2-layer LSTM ----------------
// 192 blocks x 256 threads. Blocks 0..63: layer0 (8 units each, K=512).
// Blocks 64..191: layer1 (4 units each, K=1024 over [h0_t ; h1_{t-1}]).
// Cross-WG sync: agent-scope flag counters per step; h state through MALL.
__launch_bounds__(256, 1)
__global__ void lstm_kernel(const float* __restrict__ xg0,
                            const float* __restrict__ whh0,
                            const float* __restrict__ wih1,
                            const float* __restrict__ whh1,
                            const float* __restrict__ bih1,
                            const float* __restrict__ bhh1,
                            float* __restrict__ h0s, float* __restrict__ h1s,
                            int* __restrict__ flags) {
    extern __shared__ float sm[];
    const int wg = blockIdx.x, tid = threadIdx.x;

    if (wg < 64) {
        // ----- layer 0 -----
        float* wl = sm;              // 32 cols * 512 (swizzled)
        float* hl = sm + 16384;      // 8 * 512 (swizzled)
        float* ga = sm + 20480;      // 32*8 gates
        const int wg0 = wg;
        // stage whh0 slice: col = g*8+lu -> row r = g*512 + wg0*8 + lu
#pragma unroll
        for (int p = 0; p < 16; ++p) {
            int fi = p * 256 + tid;            // float4 idx 0..4095
            int col = fi >> 7, k4 = fi & 127;
            int g = col >> 3, lu = col & 7;
            int r = g * 512 + wg0 * 8 + lu;
            float4 wv = *(const float4*)(whh0 + (size_t)r * 512 + k4 * 4);
            int widx = col * 512 + ((k4 * 4) ^ ((col & 7) << 2));
            *(float4*)(&wl[widx]) = wv;
        }
        const int col = tid >> 3, bb = tid & 7;
        const int g = col >> 3, lu = col & 7;
        const int r = g * 512 + wg0 * 8 + lu;
        const int cs = col & 7;
        const int lu2 = tid >> 3, b2 = tid & 7;   // update role for tid<64
        float c_state = 0.f;
        const float4* wp = (const float4*)wl;
        const float4* hp = (const float4*)hl;

        for (int t = 0; t < 256; ++t) {
            float xgv = xg0[(size_t)(t * 8 + bb) * 2048 + r];
            if (tid == 0 && t > 0) {
                int gd = 1 << 22;
                while (ALOADACQ(&flags[t]) < 64 && --gd) __builtin_amdgcn_s_sleep(1);
            }
            __syncthreads();
            // stage h0[t] (agent-coherent scalar loads)
#pragma unroll
            for (int p = 0; p < 16; ++p) {
                int i = p * 256 + tid;             // 0..4095
                int hb = i >> 9, k = i & 511;
                float v = ALOADR(&h0s[(size_t)t * 4096 + hb * 512 + k]);
                hl[hb * 512 + (k ^ (hb << 2))] = v;
            }
            __syncthreads();
            float4 a4 = make_float4(0, 0, 0, 0);
#pragma unroll 8
            for (int i = 0; i < 128; ++i) {
                float4 wv = wp[col * 128 + (i ^ cs)];
                float4 hv = hp[bb * 128 + (i ^ bb)];
                a4.x += wv.x * hv.x; a4.y += wv.y * hv.y;
                a4.z += wv.z * hv.z; a4.w += wv.w * hv.w;
            }
            ga[col * 8 + bb] = xgv + hsum4(a4);
            __syncthreads();
            if (tid < 64) {
                float ig = ga[(0 + lu2) * 8 + b2];
                float fg = ga[(8 + lu2) * 8 + b2];
                float gg = ga[(16 + lu2) * 8 + b2];
                float og = ga[(24 + lu2) * 8 + b2];
                c_state = sigmf(fg) * c_state + sigmf(ig) * tanhf(gg);
                float hv = sigmf(og) * tanhf(c_state);
                ASTORER(&h0s[(size_t)(t + 1) * 4096 + b2 * 512 + wg0 * 8 + lu2], hv);
            }
            __syncthreads();
            if (tid == 0) {
                __threadfence();
                __hip_atomic_fetch_add(&flags[t + 1], 1, __ATOMIC_RELEASE, __HIP_MEMORY_SCOPE_AGENT);
            }
        }
    } else {
        // ----- layer 1 -----
        float* wl = sm;              // 16 cols * 1024 (swizzled)
        float* hl = sm + 16384;      // 8 * 1024 (swizzled)
        float* ga = sm + 24576;      // 16*8
        const int wg1 = wg - 64;
#pragma unroll
        for (int p = 0; p < 16; ++p) {
            int fi = p * 256 + tid;            // float4 idx 0..4095
            int col = fi >> 8, k4 = fi & 255;
            int g = col >> 2, lu = col & 3;
            int r = g * 512 + wg1 * 4 + lu;
            int k = k4 * 4;
            float4 wv = (k < 512) ? *(const float4*)(wih1 + (size_t)r * 512 + k)
                                  : *(const float4*)(whh1 + (size_t)r * 512 + (k - 512));
            *(float4*)(&wl[col * 1024 + (k ^ ((col & 7) << 2))]) = wv;
        }
        const int col = tid >> 4, sub = tid & 15, bb = sub & 7, ks = sub >> 3;
        const int g = col >> 2, lu = col & 3;
        const int r = g * 512 + wg1 * 4 + lu;
        const float bias_r = bih1[r] + bhh1[r];
        const int cs = col & 7;
        const int lu2 = tid >> 3, b2 = tid & 7;  // update role for tid<32
        float c_state = 0.f;
        const float4* wp = (const float4*)wl;
        const float4* hp = (const float4*)hl;
        const int i0 = ks * 128;

        for (int t = 0; t < 256; ++t) {
            if (tid == 0) {
                int gd = 1 << 22;
                while (ALOADACQ(&flags[t + 1]) < 64 && --gd) __builtin_amdgcn_s_sleep(1);
                if (t > 0) {
                    gd = 1 << 22;
                    while (ALOADACQ(&flags[257 + t]) < 128 && --gd) __builtin_amdgcn_s_sleep(1);
                }
            }
            __syncthreads();
            // stage [h0_t ; h1_{t-1}]
#pragma unroll
            for (int p = 0; p < 32; ++p) {
                int i = p * 256 + tid;              // 0..8191
                int hb = i >> 10, k = i & 1023;
                const float* sp = (k < 512) ? &h0s[(size_t)(t + 1) * 4096 + hb * 512 + k]
                                            : &h1s[(size_t)t * 4096 + hb * 512 + (k - 512)];
                hl[hb * 1024 + (k ^ (hb << 2))] = ALOADR(sp);
            }
            __syncthreads();
            float4 a4 = make_float4(0, 0, 0, 0);
#pragma unroll 8
            for (int i = 0; i < 128; ++i) {
                int ii = i0 + i;
                float4 wv = wp[col * 256 + (ii ^ cs)];
                float4 hv = hp[bb * 256 + (ii ^ bb)];
                a4.x += wv.x * hv.x; a4.y += wv.y * hv.y;
                a4.z += wv.z * hv.z; a4.w += wv.w * hv.w;
            }
            float part = hsum4(a4);
            part += __shfl_xor(part, 8);
            if (ks == 0) ga[col * 8 + bb] = part + bias_r;
            __syncthreads();
            if (tid < 32) {
                float ig = ga[(0 + lu2) * 8 + b2];
                float fg = ga[(4 + lu2) * 8 + b2];
                float gg = ga[(8 + lu2) * 8 + b2];
                float og = ga[(12 + lu2) * 8 + b2];
                c_state = sigmf(fg) * c_state + sigmf(ig) * tanhf(gg);
                float hv = sigmf(og) * tanhf(c_state);
                ASTORER(&h1s[(size_t)(t + 1) * 4096 + b2 * 512 + wg1 * 4 + lu2], hv);
            }
            __syncthreads();
            if (tid == 0) {
                __threadfence();
                __hip_atomic_fetch_add(&flags[257 + t + 1], 1, __ATOMIC_RELEASE, __HIP_MEMORY_SCOPE_AGENT);
            }
        }
    }
}

// ---------------- attention (collapsed): ctx[b] = softmax(enc_p[b,:]) @ enc[b] ----------------
__launch_bounds__(256)
__global__ void attn_kernel(const float* __restrict__ enc, const float* __restrict__ attn_w,
                            float* __restrict__ ctx) {
    __shared__ float aw[512];
    __shared__ float pr[256];
    __shared__ float red[8];
    const int b = blockIdx.x, tid = threadIdx.x;
    if (tid < 128) ((float4*)aw)[tid] = ((const float4*)(attn_w + 512))[tid];
    __syncthreads();
    const float* er = enc + (size_t)(b * 256 + tid) * 512;
    float4 a4 = make_float4(0, 0, 0, 0);
#pragma unroll 8
    for (int i = 0; i < 128; ++i) {
        float4 e4 = *(const float4*)(er + i * 4);
        float4 w4 = *(const float4*)(aw + i * 4);
        a4.x += e4.x * w4.x; a4.y += e4.y * w4.y; a4.z += e4.z * w4.z; a4.w += e4.w * w4.w;
    }
    float v = hsum4(a4);
    float m = v;
#pragma unroll
    for (int off = 32; off > 0; off >>= 1) m = fmaxf(m, __shfl_xor(m, off));
    if ((tid & 63) == 0) red[tid >> 6] = m;
    __syncthreads();
    if (tid == 0) red[4] = fmaxf(fmaxf(red[0], red[1]), fmaxf(red[2], red[3]));
    __syncthreads();
    float e = expf(v - red[4]);
    pr[tid] = e;
    float s = e;
#pragma unroll
    for (int off = 32; off > 0; off >>= 1) s += __shfl_xor(s, off);
    if ((tid & 63) == 0) red[tid >> 6] = s;
    __syncthreads();
    if (tid == 0) red[5] = red[0] + red[1] + red[2] + red[3];
    __syncthreads();
    float inv = 1.f / red[5];
    for (int hh = tid; hh < 512; hh += 256) {
        float acc = 0.f;
#pragma unroll 8
        for (int s2 = 0; s2 < 256; ++s2)
            acc += pr[s2] * enc[(size_t)(b * 256 + s2) * 512 + hh];
        ctx[b * 512 + hh] = acc * inv;
    }
}

__global__ void bcast_ctx_kernel(const float* __restrict__ ctx, float* __restrict__ outc) {
    int fi = blockIdx.x * 256 + threadIdx.x;       // f4 idx, total 262144
    int h4 = fi & 127;
    int b = fi >> 15;                               // fi>>7 = (b*256+t); >>8 more = b
    ((float4*)outc)[fi] = ((const float4*)ctx)[b * 128 + h4];
}

// ---------------- output head: (b,t) row -> 10 logits ----------------
__launch_bounds__(256)
__global__ void out_proj_kernel(const float* __restrict__ h1s, const float* __restrict__ ow,
                                const float* __restrict__ ob, float* __restrict__ out) {
    int lane = threadIdx.x & 63;
    int m = blockIdx.x * 4 + (threadIdx.x >> 6);    // 0..2047, m = t*8+b
    int t = m >> 3, b = m & 7;
    const float* dr = h1s + (size_t)(t + 1) * 4096 + b * 512 + lane * 8;
    float4 d0 = *(const float4*)dr;
    float4 d1 = *(const float4*)(dr + 4);
    float acc[10];
#pragma unroll
    for (int v = 0; v < 10; ++v) {
        const float* wr = ow + v * 512 + lane * 8;
        float4 w0 = *(const float4*)wr, w1 = *(const float4*)(wr + 4);
        acc[v] = d0.x * w0.x + d0.y * w0.y + d0.z * w0.z + d0.w * w0.w +
                 d1.x * w1.x + d1.y * w1.y + d1.z * w1.z + d1.w * w1.w;
    }
#pragma unroll
    for (int v = 0; v < 10; ++v)
#pragma unroll
        for (int off = 32; off > 0; off >>= 1) acc[v] += __shfl_xor(acc[v], off);
    if (lane == 0) {
        float* o = out + (size_t)(b * 256 + t) * 10;
#pragma unroll
        for (int v = 0; v < 10; ++v) o[v] = acc[v] + ob[v];
    }
}

// ---------------- launch ----------------
extern "C" void kernel_launch(void* const* d_in, const int* in_sizes, int n_in,
                              void* d_out, int out_size, void* d_ws, size_t ws_size,
                              hipStream_t stream) {
    const int* src = (const int*)d_in[0];
    const int* tgt = (const int*)d_in[1];
    const float* emb = (const float*)d_in[2];
    const float* c1w = (const float*)d_in[3];
    const float* c1b = (const float*)d_in[4];
    const float* c2w = (const float*)d_in[5];
    const float* c2b = (const float*)d_in[6];
    const float* c3w = (const float*)d_in[7];
    const float* c3b = (const float*)d_in[8];
    const float* wih0 = (const float*)d_in[9];
    const float* whh0 = (const float*)d_in[10];
    const float* bih0 = (const float*)d_in[11];
    const float* bhh0 = (const float*)d_in[12];
    const float* wih1 = (const float*)d_in[13];
    const float* whh1 = (const float*)d_in[14];
    const float* bih1 = (const float*)d_in[15];
    const float* bhh1 = (const float*)d_in[16];
    const float* attn_w = (const float*)d_in[17];
    const float* out_w = (const float*)d_in[19];
    const float* out_b = (const float*)d_in[20];

    float* ws = (float*)d_ws;
    float* xb0 = ws + OXB0;
    float* xb1 = ws + OXB1;
    float* xb2 = ws + OXB2;
    float* enc = ws + OENC;
    float* wr1 = ws + OWR1;
    float* wr2 = ws + OWR2;
    float* wr3 = ws + OWR3;
    float* wr0 = ws + OWR0;
    float* etg = ws + OTGT;
    float* xg0 = ws + OXG0;
    float* h0s = ws + OH0S;
    float* h1s = ws + OH1S;
    float* ctx = ws + OCTX;
    int* flags = (int*)(ws + OFLG);
    float* outp = (float*)d_out;

    hipFuncSetAttribute(reinterpret_cast<const void*>(lstm_kernel),
                        hipFuncAttributeMaxDynamicSharedMemorySize, 98816);

    init_kernel<<<66, 256, 0, stream>>>(ws, flags);
    embed_src_kernel<<<2052, 256, 0, stream>>>(src, emb, xb0);
    gather_tgt_kernel<<<512, 256, 0, stream>>>(tgt, emb, etg);
    tr_conv_kernel<<<768, 256, 0, stream>>>(c1w, wr1, 256, 256);
    tr_conv_kernel<<<1536, 256, 0, stream>>>(c2w, wr2, 512, 256);
    tr_conv_kernel<<<3072, 256, 0, stream>>>(c3w, wr3, 512, 512);
    tr_mat_kernel<<<2048, 256, 0, stream>>>(wih0, wr0, 2048, 256);

    // xg0 = embtgt @ wih0^T + bih0 + bhh0   (rows ordered t*8+b)
    gemm_kernel<<<dim3(32, 32, 1), 256, 0, stream>>>(etg, 0, 256, 256, wr0, 2048,
                                                     bih0, bhh0, xg0, 0, 0);
    // conv1 + relu + pool: (8,1026,256) -> (8,514,256)
    gemm_kernel<<<dim3(16, 4, 8), 256, 0, stream>>>(xb0, 262656, 256, 768, wr1, 256,
                                                    c1b, nullptr, xb1, 131584, 1);
    // conv2 + relu + pool: (8,514,256) -> (8,258,512)
    gemm_kernel<<<dim3(8, 8, 8), 256, 0, stream>>>(xb1, 131584, 256, 768, wr2, 512,
                                                   c2b, nullptr, xb2, 132096, 1);
    // conv3 + relu: (8,258,512) -> enc (8,256,512)
    gemm_kernel<<<dim3(4, 8, 8), 256, 0, stream>>>(xb2, 132096, 512, 1536, wr3, 512,
                                                   c3b, nullptr, enc, 131072, 2);
    // persistent 2-layer LSTM
    lstm_kernel<<<192, 256, 98816, stream>>>(xg0, whh0, wih1, whh1, bih1, bhh1,
                                             h0s, h1s, flags);
    // collapsed attention + context broadcast
    attn_kernel<<<8, 256, 0, stream>>>(enc, attn_w, ctx);
    bcast_ctx_kernel<<<1024, 256, 0, stream>>>(ctx, outp + 20480);
    // output logits
    out_proj_kernel<<<512, 256, 0, stream>>>(h1s, out_w, out_b, outp);
}

// Round 2
// 2669.897 us; speedup vs baseline: 1443.0084x; 1443.0084x over previous
//
#include <hip/hip_runtime.h>
#include <cstddef>

// ---------------- constants ----------------
// B=8, S=1024, T=256, E=256, H=512, Senc=256
// ws layout (float words)
constexpr int OXB0 = 0;                         // (8, 1026, 256) padded ch-last embed(src)
constexpr int OXB1 = OXB0 + 8 * 1026 * 256;     // (8, 514, 256) after conv1+pool
constexpr int OXB2 = OXB1 + 8 * 514 * 256;      // (8, 258, 512) after conv2+pool
constexpr int OENC = OXB2 + 8 * 258 * 512;      // (8, 256, 512) enc
constexpr int OWR1 = OENC + 8 * 256 * 512;      // 768x256   conv1 W^T
constexpr int OWR2 = OWR1 + 768 * 256;          // 768x512   conv2 W^T
constexpr int OWR3 = OWR2 + 768 * 512;          // 1536x512  conv3 W^T
constexpr int OWR0 = OWR3 + 1536 * 512;         // 256x2048  wih0^T
constexpr int OTGT = OWR0 + 256 * 2048;         // 2048x256  embed(tgt), row = t*8+b
constexpr int OXG0 = OTGT + 2048 * 256;         // 2048x2048 xg0 = emb@wih0^T + biases
constexpr int OH0S = OXG0 + 2048 * 2048;        // 257*4096  h0 sequence [t][b][512]
constexpr int OH1S = OH0S + 257 * 4096;         // 257*4096  h1 sequence (dec = t>=1)
constexpr int OCTX = OH1S + 257 * 4096;         // 8*512 ctx per batch
constexpr int OFLG = OCTX + 8 * 512;            // 514*16 ints, stride-16 padded flags

constexpr int FSTR = 16;                        // 64B flag stride (line-decoupled)

__device__ __forceinline__ float hsum4(const float4& a) { return a.x + a.y + a.z + a.w; }
__device__ __forceinline__ float4 relu4(float4 v, const float4& bv) {
    v.x = fmaxf(v.x + bv.x, 0.f); v.y = fmaxf(v.y + bv.y, 0.f);
    v.z = fmaxf(v.z + bv.z, 0.f); v.w = fmaxf(v.w + bv.w, 0.f); return v;
}
__device__ __forceinline__ float4 max4(const float4& a, const float4& b) {
    float4 r; r.x = fmaxf(a.x, b.x); r.y = fmaxf(a.y, b.y);
    r.z = fmaxf(a.z, b.z); r.w = fmaxf(a.w, b.w); return r;
}
__device__ __forceinline__ float sigmf(float x) { return 1.f / (1.f + expf(-x)); }
__device__ __forceinline__ void fma4(float4& acc, const float4& a, const float4& b) {
    acc.x = fmaf(a.x, b.x, acc.x); acc.y = fmaf(a.y, b.y, acc.y);
    acc.z = fmaf(a.z, b.z, acc.z); acc.w = fmaf(a.w, b.w, acc.w);
}

__device__ __forceinline__ unsigned long long aload64(const float* p) {
    return __hip_atomic_load((const unsigned long long*)p, __ATOMIC_RELAXED,
                             __HIP_MEMORY_SCOPE_AGENT);
}
__device__ __forceinline__ void astore64(float* p, float lo, float hi) {
    unsigned long long v = ((unsigned long long)__float_as_uint(hi) << 32) |
                           (unsigned long long)__float_as_uint(lo);
    __hip_atomic_store((unsigned long long*)p, v, __ATOMIC_RELAXED,
                       __HIP_MEMORY_SCOPE_AGENT);
}
__device__ __forceinline__ float2 unpack64(unsigned long long v) {
    float2 f;
    f.x = __uint_as_float((unsigned)v);
    f.y = __uint_as_float((unsigned)(v >> 32));
    return f;
}

// ---------------- init: zero h sequences, flags, conv pad-edge rows ----------------
__global__ void init_kernel(float* __restrict__ ws, int* __restrict__ flags) {
    int idx = blockIdx.x * 256 + threadIdx.x;
    int stride = gridDim.x * 256;
    for (int i = idx; i < 257 * 4096; i += stride) {
        ws[OH0S + i] = 0.f;
        ws[OH1S + i] = 0.f;
    }
    for (int i = idx; i < 514 * FSTR; i += stride) flags[i] = 0;
    for (int i = idx; i < 8 * 2 * 256; i += stride) {
        int b = i >> 9, rr = (i >> 8) & 1, c = i & 255;
        ws[OXB1 + b * 131584 + (rr ? 513 : 0) * 256 + c] = 0.f;
    }
    for (int i = idx; i < 8 * 2 * 512; i += stride) {
        int b = i >> 10, rr = (i >> 9) & 1, c = i & 511;
        ws[OXB2 + b * 132096 + (rr ? 257 : 0) * 512 + c] = 0.f;
    }
}

// ---------------- embedding gathers ----------------
__global__ void embed_src_kernel(const int* __restrict__ src, const float* __restrict__ emb,
                                 float* __restrict__ xb0) {
    int fi = blockIdx.x * 256 + threadIdx.x;          // float4 index, total 8*1026*64
    int e4 = fi & 63;
    int r = fi >> 6;                                  // 0 .. 8*1026-1
    int b = r / 1026;
    int p = r - b * 1026;
    float4 v = make_float4(0.f, 0.f, 0.f, 0.f);
    if (p > 0 && p < 1025) {
        int row = src[b * 1024 + (p - 1)];
        v = *(const float4*)(emb + row * 256 + e4 * 4);
    }
    *(float4*)(xb0 + (size_t)fi * 4) = v;
}

__global__ void gather_tgt_kernel(const int* __restrict__ tgt, const float* __restrict__ emb,
                                  float* __restrict__ et) {
    int fi = blockIdx.x * 256 + threadIdx.x;          // total 2048*64
    int e4 = fi & 63;
    int r = fi >> 6;                                  // m = t*8 + b
    int t = r >> 3, b = r & 7;
    int row = tgt[b * 256 + t];
    *(float4*)(et + (size_t)fi * 4) = *(const float4*)(emb + row * 256 + e4 * 4);
}

// ---------------- weight transposes ----------------
__global__ void tr_conv_kernel(const float* __restrict__ w, float* __restrict__ wr,
                               int Cout, int Cin) {
    int idx = blockIdx.x * 256 + threadIdx.x;
    int co = idx / (Cin * 3);
    int rem = idx - co * Cin * 3;
    int ci = rem / 3;
    int dk = rem - ci * 3;
    wr[(dk * Cin + ci) * Cout + co] = w[idx];
}
__global__ void tr_mat_kernel(const float* __restrict__ w, float* __restrict__ wr,
                              int N, int K) {
    int idx = blockIdx.x * 256 + threadIdx.x;
    int n = idx / K;
    int k = idx - n * K;
    wr[k * N + n] = w[idx];
}

// ---------------- generic tiled GEMM (as round 0, passed) ----------------
__launch_bounds__(256)
__global__ void gemm_kernel(const float* __restrict__ A, int aBS, int RS, int K,
                            const float* __restrict__ Bw, int N,
                            const float* __restrict__ bias, const float* __restrict__ bias2,
                            float* __restrict__ out, int oBS, int mode) {
    __shared__ float As[32 * 68];
    __shared__ float Bs[32 * 64];
    const int tid = threadIdx.x;
    const int tl = tid & 15, tco = tid >> 4;
    const int m0 = blockIdx.x * 64, n0 = blockIdx.y * 64;
    const int b = blockIdx.z;
    const float* Ab = A + (size_t)b * aBS;
    float4 acc0 = make_float4(0, 0, 0, 0), acc1 = acc0, acc2 = acc0, acc3 = acc0;

    for (int k0 = 0; k0 < K; k0 += 32) {
#pragma unroll
        for (int p = 0; p < 2; ++p) {
            int f = p * 256 + tid;
            int row = f >> 3, j4 = f & 7;
            float4 av = *(const float4*)(Ab + (size_t)(m0 + row) * RS + k0 + j4 * 4);
            int kb = j4 * 4;
            As[(kb + 0) * 68 + row] = av.x;
            As[(kb + 1) * 68 + row] = av.y;
            As[(kb + 2) * 68 + row] = av.z;
            As[(kb + 3) * 68 + row] = av.w;
        }
#pragma unroll
        for (int p = 0; p < 2; ++p) {
            int f = p * 256 + tid;
            int kk = f >> 4, j4 = f & 15;
            *(float4*)(&Bs[kk * 64 + j4 * 4]) =
                *(const float4*)(Bw + (size_t)(k0 + kk) * N + n0 + j4 * 4);
        }
        __syncthreads();
#pragma unroll
        for (int kk = 0; kk < 32; ++kk) {
            float4 a4 = *(const float4*)(&As[kk * 68 + tl * 4]);
            float4 b4 = *(const float4*)(&Bs[kk * 64 + tco * 4]);
            acc0.x = fmaf(a4.x, b4.x, acc0.x); acc0.y = fmaf(a4.x, b4.y, acc0.y);
            acc0.z = fmaf(a4.x, b4.z, acc0.z); acc0.w = fmaf(a4.x, b4.w, acc0.w);
            acc1.x = fmaf(a4.y, b4.x, acc1.x); acc1.y = fmaf(a4.y, b4.y, acc1.y);
            acc1.z = fmaf(a4.y, b4.z, acc1.z); acc1.w = fmaf(a4.y, b4.w, acc1.w);
            acc2.x = fmaf(a4.z, b4.x, acc2.x); acc2.y = fmaf(a4.z, b4.y, acc2.y);
            acc2.z = fmaf(a4.z, b4.z, acc2.z); acc2.w = fmaf(a4.z, b4.w, acc2.w);
            acc3.x = fmaf(a4.w, b4.x, acc3.x); acc3.y = fmaf(a4.w, b4.y, acc3.y);
            acc3.z = fmaf(a4.w, b4.z, acc3.z); acc3.w = fmaf(a4.w, b4.w, acc3.w);
        }
        __syncthreads();
    }

    int nb = n0 + tco * 4;
    float4 bv;
    bv.x = bias[nb + 0]; bv.y = bias[nb + 1]; bv.z = bias[nb + 2]; bv.w = bias[nb + 3];
    if (bias2) { bv.x += bias2[nb + 0]; bv.y += bias2[nb + 1]; bv.z += bias2[nb + 2]; bv.w += bias2[nb + 3]; }

    if (mode == 0) {
        float4 v0 = acc0, v1 = acc1, v2 = acc2, v3 = acc3;
        v0.x += bv.x; v0.y += bv.y; v0.z += bv.z; v0.w += bv.w;
        v1.x += bv.x; v1.y += bv.y; v1.z += bv.z; v1.w += bv.w;
        v2.x += bv.x; v2.y += bv.y; v2.z += bv.z; v2.w += bv.w;
        v3.x += bv.x; v3.y += bv.y; v3.z += bv.z; v3.w += bv.w;
        int mr = m0 + tl * 4;
        *(float4*)(out + (size_t)(mr + 0) * N + nb) = v0;
        *(float4*)(out + (size_t)(mr + 1) * N + nb) = v1;
        *(float4*)(out + (size_t)(mr + 2) * N + nb) = v2;
        *(float4*)(out + (size_t)(mr + 3) * N + nb) = v3;
    } else if (mode == 1) {
        float4 v0 = relu4(acc0, bv), v1 = relu4(acc1, bv), v2 = relu4(acc2, bv), v3 = relu4(acc3, bv);
        float4 p0 = max4(v0, v1), p1 = max4(v2, v3);
        int lout = (m0 + tl * 4) >> 1;
        float* ob = out + (size_t)b * oBS + (size_t)(1 + lout) * N + nb;
        *(float4*)ob = p0;
        *(float4*)(ob + N) = p1;
    } else {
        float4 v0 = relu4(acc0, bv), v1 = relu4(acc1, bv), v2 = relu4(acc2, bv), v3 = relu4(acc3, bv);
        int mr = m0 + tl * 4;
        float* ob = out + (size_t)b * oBS + (size_t)mr * N + nb;
        *(float4*)(ob + 0 * N) = v0;
        *(float4*)(ob + 1 * N) = v1;
        *(float4*)(ob + 2 * N) = v2;
        *(float4*)(ob + 3 * N) = v3;
    }
}

// ---------------- persistent 2-layer LSTM (v2) ----------------
// 192 blocks x 256 threads, LDS-resident weights.
// Blocks 0..63: layer0, 8 hidden units each, K=512.
// Blocks 64..191: layer1, 4 hidden units each, K=1024 over [h0_t ; h1_{t-1}].
// All cross-block data: relaxed u64 agent atomics (sc0+sc1, MALL-coherent).
// Producer waves drain their own vmcnt before signaling; flags relaxed, padded.
__launch_bounds__(256, 1)
__global__ void lstm_kernel(const float* __restrict__ xg0,
                            const float* __restrict__ whh0,
                            const float* __restrict__ wih1,
                            const float* __restrict__ whh1,
                            const float* __restrict__ bih1,
                            const float* __restrict__ bhh1,
                            float* __restrict__ h0s, float* __restrict__ h1s,
                            int* __restrict__ flags) {
    extern __shared__ float sm[];
    const int wg = blockIdx.x, tid = threadIdx.x;

    if (wg < 64) {
        // ----- layer 0 -----
        float* wl = sm;              // 32 cols * 512 (swizzled)
        float* hl = sm + 16384;      // 8 * 512 (swizzled)
        float* ga = sm + 20480;      // 32*8 gates
        const int wg0 = wg;
#pragma unroll
        for (int p = 0; p < 16; ++p) {
            int fi = p * 256 + tid;            // float4 idx 0..4095
            int col = fi >> 7, k4 = fi & 127;
            int g = col >> 3, lu = col & 7;
            int r = g * 512 + wg0 * 8 + lu;
            float4 wv = *(const float4*)(whh0 + (size_t)r * 512 + k4 * 4);
            int widx = col * 512 + ((k4 * 4) ^ ((col & 7) << 2));
            *(float4*)(&wl[widx]) = wv;
        }
        // dot roles: tid = col2*16 + bb2*4 + kq
        const int col2 = tid >> 4, bb2 = (tid >> 2) & 3, kq = tid & 3;
        const int cA = col2 * 2, cB = cA + 1;
        const int bA = bb2 * 2, bB = bA + 1;
        const int csA = cA & 7, csB = cB & 7;
        const bool isw = (kq == 0);
        const int rA = (cA >> 3) * 512 + wg0 * 8 + (cA & 7);
        const int rB = (cB >> 3) * 512 + wg0 * 8 + (cB & 7);
        // update role (tid < 32): b2 batch, j2 unit-pair
        const int b2 = tid & 7, j2 = tid >> 3;
        float2 cst = make_float2(0.f, 0.f);
        const float4* wp = (const float4*)wl;
        const float4* hp = (const float4*)hl;

        float xgc0 = 0.f, xgc1 = 0.f, xgc2 = 0.f, xgc3 = 0.f;
        if (isw) {
            xgc0 = xg0[(size_t)(0 * 8 + bA) * 2048 + rA];
            xgc1 = xg0[(size_t)(0 * 8 + bB) * 2048 + rA];
            xgc2 = xg0[(size_t)(0 * 8 + bA) * 2048 + rB];
            xgc3 = xg0[(size_t)(0 * 8 + bB) * 2048 + rB];
        }

        for (int t = 0; t < 256; ++t) {
            float xgn0 = 0.f, xgn1 = 0.f, xgn2 = 0.f, xgn3 = 0.f;
            if (isw && t < 255) {
                xgn0 = xg0[(size_t)((t + 1) * 8 + bA) * 2048 + rA];
                xgn1 = xg0[(size_t)((t + 1) * 8 + bB) * 2048 + rA];
                xgn2 = xg0[(size_t)((t + 1) * 8 + bA) * 2048 + rB];
                xgn3 = xg0[(size_t)((t + 1) * 8 + bB) * 2048 + rB];
            }
            if (tid == 0 && t > 0) {
                int gd = 1 << 19;
                while (__hip_atomic_load(&flags[t * FSTR], __ATOMIC_RELAXED,
                                         __HIP_MEMORY_SCOPE_AGENT) < 64 && --gd)
                    __builtin_amdgcn_s_sleep(2);
            }
            asm volatile("" ::: "memory");
            __syncthreads();
            // stage h0[t]: 4096 floats as 2048 u64, 8/thread, two-phase
            unsigned long long tb[8];
#pragma unroll
            for (int p = 0; p < 8; ++p) {
                int i = p * 256 + tid;
                int hb = i >> 8, k0 = (i & 255) * 2;
                tb[p] = aload64(h0s + (size_t)t * 4096 + hb * 512 + k0);
            }
#pragma unroll
            for (int p = 0; p < 8; ++p) {
                int i = p * 256 + tid;
                int hb = i >> 8, k0 = (i & 255) * 2;
                *(float2*)(&hl[hb * 512 + (k0 ^ (hb << 2))]) = unpack64(tb[p]);
            }
            __syncthreads();
            // 2x2 register-blocked dot, K-quarter per thread
            float4 a00 = make_float4(0, 0, 0, 0), a01 = a00, a10 = a00, a11 = a00;
#pragma unroll 8
            for (int i = 0; i < 32; ++i) {
                int ii = kq * 32 + i;
                float4 wA = wp[cA * 128 + (ii ^ csA)];
                float4 wB = wp[cB * 128 + (ii ^ csB)];
                float4 hA = hp[bA * 128 + (ii ^ bA)];
                float4 hB = hp[bB * 128 + (ii ^ bB)];
                fma4(a00, wA, hA); fma4(a01, wA, hB);
                fma4(a10, wB, hA); fma4(a11, wB, hB);
            }
            float p00 = hsum4(a00), p01 = hsum4(a01), p10 = hsum4(a10), p11 = hsum4(a11);
            p00 += __shfl_xor(p00, 1); p00 += __shfl_xor(p00, 2);
            p01 += __shfl_xor(p01, 1); p01 += __shfl_xor(p01, 2);
            p10 += __shfl_xor(p10, 1); p10 += __shfl_xor(p10, 2);
            p11 += __shfl_xor(p11, 1); p11 += __shfl_xor(p11, 2);
            if (isw) {
                ga[cA * 8 + bA] = p00 + xgc0;
                ga[cA * 8 + bB] = p01 + xgc1;
                ga[cB * 8 + bA] = p10 + xgc2;
                ga[cB * 8 + bB] = p11 + xgc3;
            }
            __syncthreads();
            if (tid < 32) {
                float h0v = 0.f, h1v = 0.f;
#pragma unroll
                for (int e = 0; e < 2; ++e) {
                    int lu2 = j2 * 2 + e;
                    float ig = ga[(0 + lu2) * 8 + b2];
                    float fg = ga[(8 + lu2) * 8 + b2];
                    float gg = ga[(16 + lu2) * 8 + b2];
                    float og = ga[(24 + lu2) * 8 + b2];
                    float cprev = e ? cst.y : cst.x;
                    float c = sigmf(fg) * cprev + sigmf(ig) * tanhf(gg);
                    if (e) cst.y = c; else cst.x = c;
                    float h = sigmf(og) * tanhf(c);
                    if (e) h1v = h; else h0v = h;
                }
                astore64(h0s + (size_t)(t + 1) * 4096 + b2 * 512 + wg0 * 8 + j2 * 2, h0v, h1v);
            }
            if (tid < 64) asm volatile("s_waitcnt vmcnt(0)" ::: "memory");
            __syncthreads();
            if (tid == 0)
                __hip_atomic_fetch_add(&flags[(t + 1) * FSTR], 1, __ATOMIC_RELAXED,
                                       __HIP_MEMORY_SCOPE_AGENT);
            xgc0 = xgn0; xgc1 = xgn1; xgc2 = xgn2; xgc3 = xgn3;
        }
    } else {
        // ----- layer 1 -----
        float* wl = sm;              // 16 cols * 1024 (swizzled)
        float* hl = sm + 16384;      // 8 * 1024 (swizzled)
        float* ga = sm + 24576;      // 16*8
        const int wg1 = wg - 64;
#pragma unroll
        for (int p = 0; p < 16; ++p) {
            int fi = p * 256 + tid;            // float4 idx 0..4095
            int col = fi >> 8, k4 = fi & 255;
            int g = col >> 2, lu = col & 3;
            int r = g * 512 + wg1 * 4 + lu;
            int k = k4 * 4;
            float4 wv = (k < 512) ? *(const float4*)(wih1 + (size_t)r * 512 + k)
                                  : *(const float4*)(whh1 + (size_t)r * 512 + (k - 512));
            *(float4*)(&wl[col * 1024 + (k ^ ((col & 7) << 2))]) = wv;
        }
        // dot roles: tid = col2*32 + bb2*8 + kq
        const int col2 = tid >> 5, bb2 = (tid >> 3) & 3, kq = tid & 7;
        const int cA = col2 * 2, cB = cA + 1;
        const int bA = bb2 * 2, bB = bA + 1;
        const int csA = cA & 7, csB = cB & 7;
        const bool isw = (kq == 0);
        const int rA = (cA >> 2) * 512 + wg1 * 4 + (cA & 3);
        const int rB = (cB >> 2) * 512 + wg1 * 4 + (cB & 3);
        const float biasA = bih1[rA] + bhh1[rA];
        const float biasB = bih1[rB] + bhh1[rB];
        // update role (tid < 16)
        const int b2 = tid & 7, j2 = (tid >> 3) & 1;
        float2 cst = make_float2(0.f, 0.f);
        const float4* wp = (const float4*)wl;
        const float4* hp = (const float4*)hl;

        for (int t = 0; t < 256; ++t) {
            if (tid == 0) {
                int gd = 1 << 19;
                while (__hip_atomic_load(&flags[(t + 1) * FSTR], __ATOMIC_RELAXED,
                                         __HIP_MEMORY_SCOPE_AGENT) < 64 && --gd)
                    __builtin_amdgcn_s_sleep(2);
                if (t > 0) {
                    gd = 1 << 19;
                    while (__hip_atomic_load(&flags[(257 + t) * FSTR], __ATOMIC_RELAXED,
                                             __HIP_MEMORY_SCOPE_AGENT) < 128 && --gd)
                        __builtin_amdgcn_s_sleep(2);
                }
            }
            asm volatile("" ::: "memory");
            __syncthreads();
            // stage [h0_{t+1} ; h1_t]: 8192 floats as 4096 u64, 16/thread
            unsigned long long tb[16];
#pragma unroll
            for (int p = 0; p < 16; ++p) {
                int i = p * 256 + tid;
                int hb = i >> 9, k0 = (i & 511) * 2;
                const float* sp = (k0 < 512)
                    ? (h0s + (size_t)(t + 1) * 4096 + hb * 512 + k0)
                    : (h1s + (size_t)t * 4096 + hb * 512 + (k0 - 512));
                tb[p] = aload64(sp);
            }
#pragma unroll
            for (int p = 0; p < 16; ++p) {
                int i = p * 256 + tid;
                int hb = i >> 9, k0 = (i & 511) * 2;
                *(float2*)(&hl[hb * 1024 + (k0 ^ (hb << 2))]) = unpack64(tb[p]);
            }
            __syncthreads();
            // 2x2 register-blocked dot, K/8 per thread
            float4 a00 = make_float4(0, 0, 0, 0), a01 = a00, a10 = a00, a11 = a00;
#pragma unroll 8
            for (int i = 0; i < 32; ++i) {
                int ii = kq * 32 + i;
                float4 wA = wp[cA * 256 + (ii ^ csA)];
                float4 wB = wp[cB * 256 + (ii ^ csB)];
                float4 hA = hp[bA * 256 + (ii ^ bA)];
                float4 hB = hp[bB * 256 + (ii ^ bB)];
                fma4(a00, wA, hA); fma4(a01, wA, hB);
                fma4(a10, wB, hA); fma4(a11, wB, hB);
            }
            float p00 = hsum4(a00), p01 = hsum4(a01), p10 = hsum4(a10), p11 = hsum4(a11);
            p00 += __shfl_xor(p00, 1); p00 += __shfl_xor(p00, 2); p00 += __shfl_xor(p00, 4);
            p01 += __shfl_xor(p01, 1); p01 += __shfl_xor(p01, 2); p01 += __shfl_xor(p01, 4);
            p10 += __shfl_xor(p10, 1); p10 += __shfl_xor(p10, 2); p10 += __shfl_xor(p10, 4);
            p11 += __shfl_xor(p11, 1); p11 += __shfl_xor(p11, 2); p11 += __shfl_xor(p11, 4);
            if (isw) {
                ga[cA * 8 + bA] = p00 + biasA;
                ga[cA * 8 + bB] = p01 + biasA;
                ga[cB * 8 + bA] = p10 + biasB;
                ga[cB * 8 + bB] = p11 + biasB;
            }
            __syncthreads();
            if (tid < 16) {
                float h0v = 0.f, h1v = 0.f;
#pragma unroll
                for (int e = 0; e < 2; ++e) {
                    int lu2 = j2 * 2 + e;
                    float ig = ga[(0 + lu2) * 8 + b2];
                    float fg = ga[(4 + lu2) * 8 + b2];
                    float gg = ga[(8 + lu2) * 8 + b2];
                    float og = ga[(12 + lu2) * 8 + b2];
                    float cprev = e ? cst.y : cst.x;
                    float c = sigmf(fg) * cprev + sigmf(ig) * tanhf(gg);
                    if (e) cst.y = c; else cst.x = c;
                    float h = sigmf(og) * tanhf(c);
                    if (e) h1v = h; else h0v = h;
                }
                astore64(h1s + (size_t)(t + 1) * 4096 + b2 * 512 + wg1 * 4 + j2 * 2, h0v, h1v);
            }
            if (tid < 64) asm volatile("s_waitcnt vmcnt(0)" ::: "memory");
            __syncthreads();
            if (tid == 0)
                __hip_atomic_fetch_add(&flags[(257 + t + 1) * FSTR], 1, __ATOMIC_RELAXED,
                                       __HIP_MEMORY_SCOPE_AGENT);
        }
    }
}

// ---------------- attention (collapsed): ctx[b] = softmax(enc_p[b,:]) @ enc[b] ----------------
__launch_bounds__(256)
__global__ void attn_kernel(const float* __restrict__ enc, const float* __restrict__ attn_w,
                            float* __restrict__ ctx) {
    __shared__ float aw[512];
    __shared__ float pr[256];
    __shared__ float red[8];
    const int b = blockIdx.x, tid = threadIdx.x;
    if (tid < 128) ((float4*)aw)[tid] = ((const float4*)(attn_w + 512))[tid];
    __syncthreads();
    const float* er = enc + (size_t)(b * 256 + tid) * 512;
    float4 a4 = make_float4(0, 0, 0, 0);
#pragma unroll 8
    for (int i = 0; i < 128; ++i) {
        float4 e4 = *(const float4*)(er + i * 4);
        float4 w4 = *(const float4*)(aw + i * 4);
        fma4(a4, e4, w4);
    }
    float v = hsum4(a4);
    float m = v;
#pragma unroll
    for (int off = 32; off > 0; off >>= 1) m = fmaxf(m, __shfl_xor(m, off));
    if ((tid & 63) == 0) red[tid >> 6] = m;
    __syncthreads();
    if (tid == 0) red[4] = fmaxf(fmaxf(red[0], red[1]), fmaxf(red[2], red[3]));
    __syncthreads();
    float e = expf(v - red[4]);
    pr[tid] = e;
    float s = e;
#pragma unroll
    for (int off = 32; off > 0; off >>= 1) s += __shfl_xor(s, off);
    if ((tid & 63) == 0) red[tid >> 6] = s;
    __syncthreads();
    if (tid == 0) red[5] = red[0] + red[1] + red[2] + red[3];
    __syncthreads();
    float inv = 1.f / red[5];
    for (int hh = tid; hh < 512; hh += 256) {
        float acc = 0.f;
#pragma unroll 8
        for (int s2 = 0; s2 < 256; ++s2)
            acc = fmaf(pr[s2], enc[(size_t)(b * 256 + s2) * 512 + hh], acc);
        ctx[b * 512 + hh] = acc * inv;
    }
}

__global__ void bcast_ctx_kernel(const float* __restrict__ ctx, float* __restrict__ outc) {
    int fi = blockIdx.x * 256 + threadIdx.x;       // f4 idx, total 262144
    int h4 = fi & 127;
    int b = fi >> 15;
    ((float4*)outc)[fi] = ((const float4*)ctx)[b * 128 + h4];
}

// ---------------- output head: (b,t) row -> 10 logits ----------------
__launch_bounds__(256)
__global__ void out_proj_kernel(const float* __restrict__ h1s, const float* __restrict__ ow,
                                const float* __restrict__ ob, float* __restrict__ out) {
    int lane = threadIdx.x & 63;
    int m = blockIdx.x * 4 + (threadIdx.x >> 6);    // 0..2047, m = t*8+b
    int t = m >> 3, b = m & 7;
    const float* dr = h1s + (size_t)(t + 1) * 4096 + b * 512 + lane * 8;
    float4 d0 = *(const float4*)dr;
    float4 d1 = *(const float4*)(dr + 4);
    float acc[10];
#pragma unroll
    for (int v = 0; v < 10; ++v) {
        const float* wr = ow + v * 512 + lane * 8;
        float4 w0 = *(const float4*)wr, w1 = *(const float4*)(wr + 4);
        acc[v] = d0.x * w0.x + d0.y * w0.y + d0.z * w0.z + d0.w * w0.w +
                 d1.x * w1.x + d1.y * w1.y + d1.z * w1.z + d1.w * w1.w;
    }
#pragma unroll
    for (int v = 0; v < 10; ++v)
#pragma unroll
        for (int off = 32; off > 0; off >>= 1) acc[v] += __shfl_xor(acc[v], off);
    if (lane == 0) {
        float* o = out + (size_t)(b * 256 + t) * 10;
#pragma unroll
        for (int v = 0; v < 10; ++v) o[v] = acc[v] + ob[v];
    }
}

// ---------------- launch ----------------
extern "C" void kernel_launch(void* const* d_in, const int* in_sizes, int n_in,
                              void* d_out, int out_size, void* d_ws, size_t ws_size,
                              hipStream_t stream) {
    const int* src = (const int*)d_in[0];
    const int* tgt = (const int*)d_in[1];
    const float* emb = (const float*)d_in[2];
    const float* c1w = (const float*)d_in[3];
    const float* c1b = (const float*)d_in[4];
    const float* c2w = (const float*)d_in[5];
    const float* c2b = (const float*)d_in[6];
    const float* c3w = (const float*)d_in[7];
    const float* c3b = (const float*)d_in[8];
    const float* wih0 = (const float*)d_in[9];
    const float* bih0 = (const float*)d_in[11];
    const float* bhh0 = (const float*)d_in[12];
    const float* whh0 = (const float*)d_in[10];
    const float* wih1 = (const float*)d_in[13];
    const float* whh1 = (const float*)d_in[14];
    const float* bih1 = (const float*)d_in[15];
    const float* bhh1 = (const float*)d_in[16];
    const float* attn_w = (const float*)d_in[17];
    const float* out_w = (const float*)d_in[19];
    const float* out_b = (const float*)d_in[20];

    float* ws = (float*)d_ws;
    float* xb0 = ws + OXB0;
    float* xb1 = ws + OXB1;
    float* xb2 = ws + OXB2;
    float* enc = ws + OENC;
    float* wr1 = ws + OWR1;
    float* wr2 = ws + OWR2;
    float* wr3 = ws + OWR3;
    float* wr0 = ws + OWR0;
    float* etg = ws + OTGT;
    float* xg0 = ws + OXG0;
    float* h0s = ws + OH0S;
    float* h1s = ws + OH1S;
    float* ctx = ws + OCTX;
    int* flags = (int*)(ws + OFLG);
    float* outp = (float*)d_out;

    hipFuncSetAttribute(reinterpret_cast<const void*>(lstm_kernel),
                        hipFuncAttributeMaxDynamicSharedMemorySize, 98816);

    init_kernel<<<1024, 256, 0, stream>>>(ws, flags);
    embed_src_kernel<<<2052, 256, 0, stream>>>(src, emb, xb0);
    gather_tgt_kernel<<<512, 256, 0, stream>>>(tgt, emb, etg);
    tr_conv_kernel<<<768, 256, 0, stream>>>(c1w, wr1, 256, 256);
    tr_conv_kernel<<<1536, 256, 0, stream>>>(c2w, wr2, 512, 256);
    tr_conv_kernel<<<3072, 256, 0, stream>>>(c3w, wr3, 512, 512);
    tr_mat_kernel<<<2048, 256, 0, stream>>>(wih0, wr0, 2048, 256);

    // xg0 = embtgt @ wih0^T + bih0 + bhh0   (rows ordered t*8+b)
    gemm_kernel<<<dim3(32, 32, 1), 256, 0, stream>>>(etg, 0, 256, 256, wr0, 2048,
                                                     bih0, bhh0, xg0, 0, 0);
    // conv1 + relu + pool: (8,1026,256) -> (8,514,256)
    gemm_kernel<<<dim3(16, 4, 8), 256, 0, stream>>>(xb0, 262656, 256, 768, wr1, 256,
                                                    c1b, nullptr, xb1, 131584, 1);
    // conv2 + relu + pool: (8,514,256) -> (8,258,512)
    gemm_kernel<<<dim3(8, 8, 8), 256, 0, stream>>>(xb1, 131584, 256, 768, wr2, 512,
                                                   c2b, nullptr, xb2, 132096, 1);
    // conv3 + relu: (8,258,512) -> enc (8,256,512)
    gemm_kernel<<<dim3(4, 8, 8), 256, 0, stream>>>(xb2, 132096, 512, 1536, wr3, 512,
                                                   c3b, nullptr, enc, 131072, 2);
    // persistent 2-layer LSTM
    lstm_kernel<<<192, 256, 98816, stream>>>(xg0, whh0, wih1, whh1, bih1, bhh1,
                                             h0s, h1s, flags);
    // collapsed attention + context broadcast
    attn_kernel<<<8, 256, 0, stream>>>(enc, attn_w, ctx);
    bcast_ctx_kernel<<<1024, 256, 0, stream>>>(ctx, outp + 20480);
    // output logits
    out_proj_kernel<<<512, 256, 0, stream>>>(h1s, out_w, out_b, outp);
}

// Round 3
// 2547.544 us; speedup vs baseline: 1512.3132x; 1.0480x over previous
//
#include <hip/hip_runtime.h>
#include <cstddef>

// ---------------- constants ----------------
// B=8, S=1024, T=256, E=256, H=512, Senc=256
// ws layout (float words)
constexpr int OXB0 = 0;                         // (8, 1026, 256) padded ch-last embed(src)
constexpr int OXB1 = OXB0 + 8 * 1026 * 256;     // (8, 514, 256) after conv1+pool
constexpr int OXB2 = OXB1 + 8 * 514 * 256;      // (8, 258, 512) after conv2+pool
constexpr int OENC = OXB2 + 8 * 258 * 512;      // (8, 256, 512) enc
constexpr int OWR1 = OENC + 8 * 256 * 512;      // 768x256   conv1 W^T
constexpr int OWR2 = OWR1 + 768 * 256;          // 768x512   conv2 W^T
constexpr int OWR3 = OWR2 + 768 * 512;          // 1536x512  conv3 W^T
constexpr int OWR0 = OWR3 + 1536 * 512;         // 256x2048  wih0^T
constexpr int OTGT = OWR0 + 256 * 2048;         // 2048x256  embed(tgt), row = t*8+b
constexpr int OXG0 = OTGT + 2048 * 256;         // 2048x2048 xg0 = emb@wih0^T + biases
constexpr int OH0S = OXG0 + 2048 * 2048;        // 257*4096  h0 sequence [t][b][512]
constexpr int OH1S = OH0S + 257 * 4096;         // 257*4096  h1 sequence (dec = t>=1)
constexpr int OCTX = OH1S + 257 * 4096;         // 8*512 ctx per batch
constexpr int OFLG = OCTX + 8 * 512;            // 514*16 ints, stride-16 padded flags

constexpr int FSTR = 16;                        // 64B flag stride (line-decoupled)

__device__ __forceinline__ float hsum4(const float4& a) { return a.x + a.y + a.z + a.w; }
__device__ __forceinline__ float4 relu4(float4 v, const float4& bv) {
    v.x = fmaxf(v.x + bv.x, 0.f); v.y = fmaxf(v.y + bv.y, 0.f);
    v.z = fmaxf(v.z + bv.z, 0.f); v.w = fmaxf(v.w + bv.w, 0.f); return v;
}
__device__ __forceinline__ float4 max4(const float4& a, const float4& b) {
    float4 r; r.x = fmaxf(a.x, b.x); r.y = fmaxf(a.y, b.y);
    r.z = fmaxf(a.z, b.z); r.w = fmaxf(a.w, b.w); return r;
}
__device__ __forceinline__ float sigmf(float x) { return 1.f / (1.f + expf(-x)); }
__device__ __forceinline__ void fma4(float4& acc, const float4& a, const float4& b) {
    acc.x = fmaf(a.x, b.x, acc.x); acc.y = fmaf(a.y, b.y, acc.y);
    acc.z = fmaf(a.z, b.z, acc.z); acc.w = fmaf(a.w, b.w, acc.w);
}

__device__ __forceinline__ unsigned long long aload64(const float* p) {
    return __hip_atomic_load((const unsigned long long*)p, __ATOMIC_RELAXED,
                             __HIP_MEMORY_SCOPE_AGENT);
}
__device__ __forceinline__ void astore32(float* p, float v) {
    __hip_atomic_store((unsigned int*)p, __float_as_uint(v), __ATOMIC_RELAXED,
                       __HIP_MEMORY_SCOPE_AGENT);
}
__device__ __forceinline__ float2 unpack64(unsigned long long v) {
    float2 f;
    f.x = __uint_as_float((unsigned)v);
    f.y = __uint_as_float((unsigned)(v >> 32));
    return f;
}
// compile-time-register 4-way select (no runtime-indexed reg arrays)
__device__ __forceinline__ float sel4f(int i, float a, float b, float c, float d) {
    float ab = (i & 1) ? b : a;
    float cd = (i & 1) ? d : c;
    return (i & 2) ? cd : ab;
}
#define SEL8(S) (oe ? sel4f(obi, (S)[1][0], (S)[1][1], (S)[1][2], (S)[1][3]) \
                    : sel4f(obi, (S)[0][0], (S)[0][1], (S)[0][2], (S)[0][3]))

// ---------------- init: zero h sequences, flags, conv pad-edge rows ----------------
__global__ void init_kernel(float* __restrict__ ws, int* __restrict__ flags) {
    int idx = blockIdx.x * 256 + threadIdx.x;
    int stride = gridDim.x * 256;
    for (int i = idx; i < 257 * 4096; i += stride) {
        ws[OH0S + i] = 0.f;
        ws[OH1S + i] = 0.f;
    }
    for (int i = idx; i < 514 * FSTR; i += stride) flags[i] = 0;
    for (int i = idx; i < 8 * 2 * 256; i += stride) {
        int b = i >> 9, rr = (i >> 8) & 1, c = i & 255;
        ws[OXB1 + b * 131584 + (rr ? 513 : 0) * 256 + c] = 0.f;
    }
    for (int i = idx; i < 8 * 2 * 512; i += stride) {
        int b = i >> 10, rr = (i >> 9) & 1, c = i & 511;
        ws[OXB2 + b * 132096 + (rr ? 257 : 0) * 512 + c] = 0.f;
    }
}

// ---------------- embedding gathers ----------------
__global__ void embed_src_kernel(const int* __restrict__ src, const float* __restrict__ emb,
                                 float* __restrict__ xb0) {
    int fi = blockIdx.x * 256 + threadIdx.x;          // float4 index, total 8*1026*64
    int e4 = fi & 63;
    int r = fi >> 6;                                  // 0 .. 8*1026-1
    int b = r / 1026;
    int p = r - b * 1026;
    float4 v = make_float4(0.f, 0.f, 0.f, 0.f);
    if (p > 0 && p < 1025) {
        int row = src[b * 1024 + (p - 1)];
        v = *(const float4*)(emb + row * 256 + e4 * 4);
    }
    *(float4*)(xb0 + (size_t)fi * 4) = v;
}

__global__ void gather_tgt_kernel(const int* __restrict__ tgt, const float* __restrict__ emb,
                                  float* __restrict__ et) {
    int fi = blockIdx.x * 256 + threadIdx.x;          // total 2048*64
    int e4 = fi & 63;
    int r = fi >> 6;                                  // m = t*8 + b
    int t = r >> 3, b = r & 7;
    int row = tgt[b * 256 + t];
    *(float4*)(et + (size_t)fi * 4) = *(const float4*)(emb + row * 256 + e4 * 4);
}

// ---------------- weight transposes ----------------
__global__ void tr_conv_kernel(const float* __restrict__ w, float* __restrict__ wr,
                               int Cout, int Cin) {
    int idx = blockIdx.x * 256 + threadIdx.x;
    int co = idx / (Cin * 3);
    int rem = idx - co * Cin * 3;
    int ci = rem / 3;
    int dk = rem - ci * 3;
    wr[(dk * Cin + ci) * Cout + co] = w[idx];
}
__global__ void tr_mat_kernel(const float* __restrict__ w, float* __restrict__ wr,
                              int N, int K) {
    int idx = blockIdx.x * 256 + threadIdx.x;
    int n = idx / K;
    int k = idx - n * K;
    wr[k * N + n] = w[idx];
}

// ---------------- generic tiled GEMM (unchanged, passing) ----------------
__launch_bounds__(256)
__global__ void gemm_kernel(const float* __restrict__ A, int aBS, int RS, int K,
                            const float* __restrict__ Bw, int N,
                            const float* __restrict__ bias, const float* __restrict__ bias2,
                            float* __restrict__ out, int oBS, int mode) {
    __shared__ float As[32 * 68];
    __shared__ float Bs[32 * 64];
    const int tid = threadIdx.x;
    const int tl = tid & 15, tco = tid >> 4;
    const int m0 = blockIdx.x * 64, n0 = blockIdx.y * 64;
    const int b = blockIdx.z;
    const float* Ab = A + (size_t)b * aBS;
    float4 acc0 = make_float4(0, 0, 0, 0), acc1 = acc0, acc2 = acc0, acc3 = acc0;

    for (int k0 = 0; k0 < K; k0 += 32) {
#pragma unroll
        for (int p = 0; p < 2; ++p) {
            int f = p * 256 + tid;
            int row = f >> 3, j4 = f & 7;
            float4 av = *(const float4*)(Ab + (size_t)(m0 + row) * RS + k0 + j4 * 4);
            int kb = j4 * 4;
            As[(kb + 0) * 68 + row] = av.x;
            As[(kb + 1) * 68 + row] = av.y;
            As[(kb + 2) * 68 + row] = av.z;
            As[(kb + 3) * 68 + row] = av.w;
        }
#pragma unroll
        for (int p = 0; p < 2; ++p) {
            int f = p * 256 + tid;
            int kk = f >> 4, j4 = f & 15;
            *(float4*)(&Bs[kk * 64 + j4 * 4]) =
                *(const float4*)(Bw + (size_t)(k0 + kk) * N + n0 + j4 * 4);
        }
        __syncthreads();
#pragma unroll
        for (int kk = 0; kk < 32; ++kk) {
            float4 a4 = *(const float4*)(&As[kk * 68 + tl * 4]);
            float4 b4 = *(const float4*)(&Bs[kk * 64 + tco * 4]);
            acc0.x = fmaf(a4.x, b4.x, acc0.x); acc0.y = fmaf(a4.x, b4.y, acc0.y);
            acc0.z = fmaf(a4.x, b4.z, acc0.z); acc0.w = fmaf(a4.x, b4.w, acc0.w);
            acc1.x = fmaf(a4.y, b4.x, acc1.x); acc1.y = fmaf(a4.y, b4.y, acc1.y);
            acc1.z = fmaf(a4.y, b4.z, acc1.z); acc1.w = fmaf(a4.y, b4.w, acc1.w);
            acc2.x = fmaf(a4.z, b4.x, acc2.x); acc2.y = fmaf(a4.z, b4.y, acc2.y);
            acc2.z = fmaf(a4.z, b4.z, acc2.z); acc2.w = fmaf(a4.z, b4.w, acc2.w);
            acc3.x = fmaf(a4.w, b4.x, acc3.x); acc3.y = fmaf(a4.w, b4.y, acc3.y);
            acc3.z = fmaf(a4.w, b4.z, acc3.z); acc3.w = fmaf(a4.w, b4.w, acc3.w);
        }
        __syncthreads();
    }

    int nb = n0 + tco * 4;
    float4 bv;
    bv.x = bias[nb + 0]; bv.y = bias[nb + 1]; bv.z = bias[nb + 2]; bv.w = bias[nb + 3];
    if (bias2) { bv.x += bias2[nb + 0]; bv.y += bias2[nb + 1]; bv.z += bias2[nb + 2]; bv.w += bias2[nb + 3]; }

    if (mode == 0) {
        float4 v0 = acc0, v1 = acc1, v2 = acc2, v3 = acc3;
        v0.x += bv.x; v0.y += bv.y; v0.z += bv.z; v0.w += bv.w;
        v1.x += bv.x; v1.y += bv.y; v1.z += bv.z; v1.w += bv.w;
        v2.x += bv.x; v2.y += bv.y; v2.z += bv.z; v2.w += bv.w;
        v3.x += bv.x; v3.y += bv.y; v3.z += bv.z; v3.w += bv.w;
        int mr = m0 + tl * 4;
        *(float4*)(out + (size_t)(mr + 0) * N + nb) = v0;
        *(float4*)(out + (size_t)(mr + 1) * N + nb) = v1;
        *(float4*)(out + (size_t)(mr + 2) * N + nb) = v2;
        *(float4*)(out + (size_t)(mr + 3) * N + nb) = v3;
    } else if (mode == 1) {
        float4 v0 = relu4(acc0, bv), v1 = relu4(acc1, bv), v2 = relu4(acc2, bv), v3 = relu4(acc3, bv);
        float4 p0 = max4(v0, v1), p1 = max4(v2, v3);
        int lout = (m0 + tl * 4) >> 1;
        float* ob = out + (size_t)b * oBS + (size_t)(1 + lout) * N + nb;
        *(float4*)ob = p0;
        *(float4*)(ob + N) = p1;
    } else {
        float4 v0 = relu4(acc0, bv), v1 = relu4(acc1, bv), v2 = relu4(acc2, bv), v3 = relu4(acc3, bv);
        int mr = m0 + tl * 4;
        float* ob = out + (size_t)b * oBS + (size_t)mr * N + nb;
        *(float4*)(ob + 0 * N) = v0;
        *(float4*)(ob + 1 * N) = v1;
        *(float4*)(ob + 2 * N) = v2;
        *(float4*)(ob + 3 * N) = v3;
    }
}

// ---------------- persistent 2-layer LSTM (v3: zero-LDS, W-in-regs) ----------------
// 192 blocks x 256 threads, 1 block/CU.
// Blocks 0..63: layer0 (8 units). Waves = colgroup cg 0..3 (units cg*2+{0,1}).
//   Lane: bg = (tid>>5)&1 selects batches bg*4..+3; ks = tid&31 owns k = q*64+ks*2+{0,1}.
//   Reduce: 5-level shfl_xor butterfly within 32 lanes.
// Blocks 64..191: layer1 (4 units). Wave w: cg=w>>1 (units cg*2+{0,1}), bgv=w&1
//   (batches bgv*4..+3); ks = tid&63 owns k = q*128+ks*2+{0,1} over [h0_t+1 ; h1_t].
//   Reduce: 6-level butterfly over full wave.
// W lives in VGPRs; h staged global->reg via coalesced relaxed u64 agent atomics.
// Sync: relaxed polls, per-wave vmcnt(0) drain, __syncthreads, one fetch_add/block.
__launch_bounds__(256, 1)
__global__ void lstm_kernel(const float* __restrict__ xg0,
                            const float* __restrict__ whh0,
                            const float* __restrict__ wih1,
                            const float* __restrict__ whh1,
                            const float* __restrict__ bih1,
                            const float* __restrict__ bhh1,
                            float* __restrict__ h0s, float* __restrict__ h1s,
                            int* __restrict__ flags) {
    const int tid = threadIdx.x;
    const int wg = blockIdx.x;

    if (wg < 64) {
        // ----- layer 0 -----
        const int wg0 = wg;
        const int cg = tid >> 6;          // wave id = colgroup
        const int bg = (tid >> 5) & 1;
        const int ks = tid & 31;
        // W[g][e][q] = whh0[(g*512 + wg0*8 + cg*2 + e)*512 + q*64 + ks*2 +{0,1}]
        float2 W2[4][2][8];
#pragma unroll
        for (int g = 0; g < 4; ++g)
#pragma unroll
            for (int e = 0; e < 2; ++e) {
                const float* wr = whh0 + (size_t)(g * 512 + wg0 * 8 + cg * 2 + e) * 512 + ks * 2;
#pragma unroll
                for (int q = 0; q < 8; ++q)
                    W2[g][e][q] = *(const float2*)(wr + q * 64);
            }
        const bool own = (ks < 8);
        const int oe = (ks >> 2) & 1, obi = ks & 3, ob = bg * 4 + obi;
        float cst = 0.f;

        for (int t = 0; t < 256; ++t) {
            if (tid == 0 && t > 0) {
                int gd = 1 << 20;
                while (__hip_atomic_load(&flags[t * FSTR], __ATOMIC_RELAXED,
                                         __HIP_MEMORY_SCOPE_AGENT) < 64 && --gd)
                    __builtin_amdgcn_s_sleep(2);
            }
            __syncthreads();
            // h0[t] loads: coalesced (lanes ks*2 contiguous within each (bi,q))
            unsigned long long hv[4][8];
#pragma unroll
            for (int bi = 0; bi < 4; ++bi) {
                const float* hb = h0s + (size_t)t * 4096 + (bg * 4 + bi) * 512 + ks * 2;
#pragma unroll
                for (int q = 0; q < 8; ++q)
                    hv[bi][q] = aload64(hb + q * 64);
            }
            float xgv0 = 0.f, xgv1 = 0.f, xgv2 = 0.f, xgv3 = 0.f;
            if (own) {
                const float* xr = xg0 + (size_t)(t * 8 + ob) * 2048 + wg0 * 8 + cg * 2 + oe;
                xgv0 = xr[0]; xgv1 = xr[512]; xgv2 = xr[1024]; xgv3 = xr[1536];
            }
            float2 acc[4][2][4];
#pragma unroll
            for (int g = 0; g < 4; ++g)
#pragma unroll
                for (int e = 0; e < 2; ++e)
#pragma unroll
                    for (int bi = 0; bi < 4; ++bi) acc[g][e][bi] = make_float2(0.f, 0.f);
#pragma unroll
            for (int q = 0; q < 8; ++q)
#pragma unroll
                for (int bi = 0; bi < 4; ++bi) {
                    float2 h2 = unpack64(hv[bi][q]);
#pragma unroll
                    for (int g = 0; g < 4; ++g)
#pragma unroll
                        for (int e = 0; e < 2; ++e) {
                            acc[g][e][bi].x = fmaf(W2[g][e][q].x, h2.x, acc[g][e][bi].x);
                            acc[g][e][bi].y = fmaf(W2[g][e][q].y, h2.y, acc[g][e][bi].y);
                        }
                }
            float s[4][2][4];
#pragma unroll
            for (int g = 0; g < 4; ++g)
#pragma unroll
                for (int e = 0; e < 2; ++e)
#pragma unroll
                    for (int bi = 0; bi < 4; ++bi) s[g][e][bi] = acc[g][e][bi].x + acc[g][e][bi].y;
#pragma unroll
            for (int lvl = 1; lvl <= 16; lvl <<= 1)
#pragma unroll
                for (int g = 0; g < 4; ++g)
#pragma unroll
                    for (int e = 0; e < 2; ++e)
#pragma unroll
                        for (int bi = 0; bi < 4; ++bi)
                            s[g][e][bi] += __shfl_xor(s[g][e][bi], lvl);
            if (own) {
                float ig = SEL8(s[0]) + xgv0;
                float fg = SEL8(s[1]) + xgv1;
                float gg = SEL8(s[2]) + xgv2;
                float og = SEL8(s[3]) + xgv3;
                cst = sigmf(fg) * cst + sigmf(ig) * tanhf(gg);
                float hval = sigmf(og) * tanhf(cst);
                astore32(h0s + (size_t)(t + 1) * 4096 + ob * 512 + wg0 * 8 + cg * 2 + oe, hval);
            }
            asm volatile("s_waitcnt vmcnt(0)" ::: "memory");
            __syncthreads();
            if (tid == 0)
                __hip_atomic_fetch_add(&flags[(t + 1) * FSTR], 1, __ATOMIC_RELAXED,
                                       __HIP_MEMORY_SCOPE_AGENT);
        }
    } else {
        // ----- layer 1 -----
        const int wg1 = wg - 64;
        const int w = tid >> 6;
        const int cg = w >> 1, bgv = w & 1;
        const int ks = tid & 63;
        // k(q) = q*128 + ks*2; q<4 -> ih-part (h0_{t+1}), q>=4 -> hh-part (h1_t)
        float2 W2[4][2][8];
#pragma unroll
        for (int g = 0; g < 4; ++g)
#pragma unroll
            for (int e = 0; e < 2; ++e) {
                const size_t ro = (size_t)(g * 512 + wg1 * 4 + cg * 2 + e) * 512 + ks * 2;
#pragma unroll
                for (int q = 0; q < 4; ++q)
                    W2[g][e][q] = *(const float2*)(wih1 + ro + q * 128);
#pragma unroll
                for (int q = 4; q < 8; ++q)
                    W2[g][e][q] = *(const float2*)(whh1 + ro + (q - 4) * 128);
            }
        const bool own = (ks < 8);
        const int oe = (ks >> 2) & 1, obi = ks & 3, ob = bgv * 4 + obi;
        float bs0 = 0.f, bs1 = 0.f, bs2 = 0.f, bs3 = 0.f;
        if (own) {
            int rb = wg1 * 4 + cg * 2 + oe;
            bs0 = bih1[rb] + bhh1[rb];
            bs1 = bih1[512 + rb] + bhh1[512 + rb];
            bs2 = bih1[1024 + rb] + bhh1[1024 + rb];
            bs3 = bih1[1536 + rb] + bhh1[1536 + rb];
        }
        float cst = 0.f;

        for (int t = 0; t < 256; ++t) {
            if (tid == 0) {
                int gd = 1 << 20;
                while (__hip_atomic_load(&flags[(t + 1) * FSTR], __ATOMIC_RELAXED,
                                         __HIP_MEMORY_SCOPE_AGENT) < 64 && --gd)
                    __builtin_amdgcn_s_sleep(2);
                if (t > 0) {
                    gd = 1 << 20;
                    while (__hip_atomic_load(&flags[(257 + t) * FSTR], __ATOMIC_RELAXED,
                                             __HIP_MEMORY_SCOPE_AGENT) < 128 && --gd)
                        __builtin_amdgcn_s_sleep(2);
                }
            }
            __syncthreads();
            unsigned long long hv[4][8];
#pragma unroll
            for (int bi = 0; bi < 4; ++bi) {
                const float* h0b = h0s + (size_t)(t + 1) * 4096 + (bgv * 4 + bi) * 512 + ks * 2;
                const float* h1b = h1s + (size_t)t * 4096 + (bgv * 4 + bi) * 512 + ks * 2;
#pragma unroll
                for (int q = 0; q < 4; ++q) hv[bi][q] = aload64(h0b + q * 128);
#pragma unroll
                for (int q = 4; q < 8; ++q) hv[bi][q] = aload64(h1b + (q - 4) * 128);
            }
            float2 acc[4][2][4];
#pragma unroll
            for (int g = 0; g < 4; ++g)
#pragma unroll
                for (int e = 0; e < 2; ++e)
#pragma unroll
                    for (int bi = 0; bi < 4; ++bi) acc[g][e][bi] = make_float2(0.f, 0.f);
#pragma unroll
            for (int q = 0; q < 8; ++q)
#pragma unroll
                for (int bi = 0; bi < 4; ++bi) {
                    float2 h2 = unpack64(hv[bi][q]);
#pragma unroll
                    for (int g = 0; g < 4; ++g)
#pragma unroll
                        for (int e = 0; e < 2; ++e) {
                            acc[g][e][bi].x = fmaf(W2[g][e][q].x, h2.x, acc[g][e][bi].x);
                            acc[g][e][bi].y = fmaf(W2[g][e][q].y, h2.y, acc[g][e][bi].y);
                        }
                }
            float s[4][2][4];
#pragma unroll
            for (int g = 0; g < 4; ++g)
#pragma unroll
                for (int e = 0; e < 2; ++e)
#pragma unroll
                    for (int bi = 0; bi < 4; ++bi) s[g][e][bi] = acc[g][e][bi].x + acc[g][e][bi].y;
#pragma unroll
            for (int lvl = 1; lvl <= 32; lvl <<= 1)
#pragma unroll
                for (int g = 0; g < 4; ++g)
#pragma unroll
                    for (int e = 0; e < 2; ++e)
#pragma unroll
                        for (int bi = 0; bi < 4; ++bi)
                            s[g][e][bi] += __shfl_xor(s[g][e][bi], lvl);
            if (own) {
                float ig = SEL8(s[0]) + bs0;
                float fg = SEL8(s[1]) + bs1;
                float gg = SEL8(s[2]) + bs2;
                float og = SEL8(s[3]) + bs3;
                cst = sigmf(fg) * cst + sigmf(ig) * tanhf(gg);
                float hval = sigmf(og) * tanhf(cst);
                astore32(h1s + (size_t)(t + 1) * 4096 + ob * 512 + wg1 * 4 + cg * 2 + oe, hval);
            }
            asm volatile("s_waitcnt vmcnt(0)" ::: "memory");
            __syncthreads();
            if (tid == 0)
                __hip_atomic_fetch_add(&flags[(257 + t + 1) * FSTR], 1, __ATOMIC_RELAXED,
                                       __HIP_MEMORY_SCOPE_AGENT);
        }
    }
}

// ---------------- attention (collapsed): ctx[b] = softmax(enc_p[b,:]) @ enc[b] ----------------
__launch_bounds__(256)
__global__ void attn_kernel(const float* __restrict__ enc, const float* __restrict__ attn_w,
                            float* __restrict__ ctx) {
    __shared__ float aw[512];
    __shared__ float pr[256];
    __shared__ float red[8];
    const int b = blockIdx.x, tid = threadIdx.x;
    if (tid < 128) ((float4*)aw)[tid] = ((const float4*)(attn_w + 512))[tid];
    __syncthreads();
    const float* er = enc + (size_t)(b * 256 + tid) * 512;
    float4 a4 = make_float4(0, 0, 0, 0);
#pragma unroll 8
    for (int i = 0; i < 128; ++i) {
        float4 e4 = *(const float4*)(er + i * 4);
        float4 w4 = *(const float4*)(aw + i * 4);
        fma4(a4, e4, w4);
    }
    float v = hsum4(a4);
    float m = v;
#pragma unroll
    for (int off = 32; off > 0; off >>= 1) m = fmaxf(m, __shfl_xor(m, off));
    if ((tid & 63) == 0) red[tid >> 6] = m;
    __syncthreads();
    if (tid == 0) red[4] = fmaxf(fmaxf(red[0], red[1]), fmaxf(red[2], red[3]));
    __syncthreads();
    float e = expf(v - red[4]);
    pr[tid] = e;
    float s = e;
#pragma unroll
    for (int off = 32; off > 0; off >>= 1) s += __shfl_xor(s, off);
    if ((tid & 63) == 0) red[tid >> 6] = s;
    __syncthreads();
    if (tid == 0) red[5] = red[0] + red[1] + red[2] + red[3];
    __syncthreads();
    float inv = 1.f / red[5];
    for (int hh = tid; hh < 512; hh += 256) {
        float acc = 0.f;
#pragma unroll 8
        for (int s2 = 0; s2 < 256; ++s2)
            acc = fmaf(pr[s2], enc[(size_t)(b * 256 + s2) * 512 + hh], acc);
        ctx[b * 512 + hh] = acc * inv;
    }
}

__global__ void bcast_ctx_kernel(const float* __restrict__ ctx, float* __restrict__ outc) {
    int fi = blockIdx.x * 256 + threadIdx.x;       // f4 idx, total 262144
    int h4 = fi & 127;
    int b = fi >> 15;
    ((float4*)outc)[fi] = ((const float4*)ctx)[b * 128 + h4];
}

// ---------------- output head: (b,t) row -> 10 logits ----------------
__launch_bounds__(256)
__global__ void out_proj_kernel(const float* __restrict__ h1s, const float* __restrict__ ow,
                                const float* __restrict__ ob, float* __restrict__ out) {
    int lane = threadIdx.x & 63;
    int m = blockIdx.x * 4 + (threadIdx.x >> 6);    // 0..2047, m = t*8+b
    int t = m >> 3, b = m & 7;
    const float* dr = h1s + (size_t)(t + 1) * 4096 + b * 512 + lane * 8;
    float4 d0 = *(const float4*)dr;
    float4 d1 = *(const float4*)(dr + 4);
    float acc[10];
#pragma unroll
    for (int v = 0; v < 10; ++v) {
        const float* wr = ow + v * 512 + lane * 8;
        float4 w0 = *(const float4*)wr, w1 = *(const float4*)(wr + 4);
        acc[v] = d0.x * w0.x + d0.y * w0.y + d0.z * w0.z + d0.w * w0.w +
                 d1.x * w1.x + d1.y * w1.y + d1.z * w1.z + d1.w * w1.w;
    }
#pragma unroll
    for (int v = 0; v < 10; ++v)
#pragma unroll
        for (int off = 32; off > 0; off >>= 1) acc[v] += __shfl_xor(acc[v], off);
    if (lane == 0) {
        float* o = out + (size_t)(b * 256 + t) * 10;
#pragma unroll
        for (int v = 0; v < 10; ++v) o[v] = acc[v] + ob[v];
    }
}

// ---------------- launch ----------------
extern "C" void kernel_launch(void* const* d_in, const int* in_sizes, int n_in,
                              void* d_out, int out_size, void* d_ws, size_t ws_size,
                              hipStream_t stream) {
    const int* src = (const int*)d_in[0];
    const int* tgt = (const int*)d_in[1];
    const float* emb = (const float*)d_in[2];
    const float* c1w = (const float*)d_in[3];
    const float* c1b = (const float*)d_in[4];
    const float* c2w = (const float*)d_in[5];
    const float* c2b = (const float*)d_in[6];
    const float* c3w = (const float*)d_in[7];
    const float* c3b = (const float*)d_in[8];
    const float* wih0 = (const float*)d_in[9];
    const float* whh0 = (const float*)d_in[10];
    const float* bih0 = (const float*)d_in[11];
    const float* bhh0 = (const float*)d_in[12];
    const float* wih1 = (const float*)d_in[13];
    const float* whh1 = (const float*)d_in[14];
    const float* bih1 = (const float*)d_in[15];
    const float* bhh1 = (const float*)d_in[16];
    const float* attn_w = (const float*)d_in[17];
    const float* out_w = (const float*)d_in[19];
    const float* out_b = (const float*)d_in[20];

    float* ws = (float*)d_ws;
    float* xb0 = ws + OXB0;
    float* xb1 = ws + OXB1;
    float* xb2 = ws + OXB2;
    float* enc = ws + OENC;
    float* wr1 = ws + OWR1;
    float* wr2 = ws + OWR2;
    float* wr3 = ws + OWR3;
    float* wr0 = ws + OWR0;
    float* etg = ws + OTGT;
    float* xg0 = ws + OXG0;
    float* h0s = ws + OH0S;
    float* h1s = ws + OH1S;
    float* ctx = ws + OCTX;
    int* flags = (int*)(ws + OFLG);
    float* outp = (float*)d_out;

    init_kernel<<<1024, 256, 0, stream>>>(ws, flags);
    embed_src_kernel<<<2052, 256, 0, stream>>>(src, emb, xb0);
    gather_tgt_kernel<<<512, 256, 0, stream>>>(tgt, emb, etg);
    tr_conv_kernel<<<768, 256, 0, stream>>>(c1w, wr1, 256, 256);
    tr_conv_kernel<<<1536, 256, 0, stream>>>(c2w, wr2, 512, 256);
    tr_conv_kernel<<<3072, 256, 0, stream>>>(c3w, wr3, 512, 512);
    tr_mat_kernel<<<2048, 256, 0, stream>>>(wih0, wr0, 2048, 256);

    // xg0 = embtgt @ wih0^T + bih0 + bhh0   (rows ordered t*8+b)
    gemm_kernel<<<dim3(32, 32, 1), 256, 0, stream>>>(etg, 0, 256, 256, wr0, 2048,
                                                     bih0, bhh0, xg0, 0, 0);
    // conv1 + relu + pool: (8,1026,256) -> (8,514,256)
    gemm_kernel<<<dim3(16, 4, 8), 256, 0, stream>>>(xb0, 262656, 256, 768, wr1, 256,
                                                    c1b, nullptr, xb1, 131584, 1);
    // conv2 + relu + pool: (8,514,256) -> (8,258,512)
    gemm_kernel<<<dim3(8, 8, 8), 256, 0, stream>>>(xb1, 131584, 256, 768, wr2, 512,
                                                   c2b, nullptr, xb2, 132096, 1);
    // conv3 + relu: (8,258,512) -> enc (8,256,512)
    gemm_kernel<<<dim3(4, 8, 8), 256, 0, stream>>>(xb2, 132096, 512, 1536, wr3, 512,
                                                   c3b, nullptr, enc, 131072, 2);
    // persistent 2-layer LSTM (no dynamic LDS)
    lstm_kernel<<<192, 256, 0, stream>>>(xg0, whh0, wih1, whh1, bih1, bhh1,
                                         h0s, h1s, flags);
    // collapsed attention + context broadcast
    attn_kernel<<<8, 256, 0, stream>>>(enc, attn_w, ctx);
    bcast_ctx_kernel<<<1024, 256, 0, stream>>>(ctx, outp + 20480);
    // output logits
    out_proj_kernel<<<512, 256, 0, stream>>>(h1s, out_w, out_b, outp);
}

// Round 5
// 1433.904 us; speedup vs baseline: 2686.8484x; 1.7766x over previous
//
#include <hip/hip_runtime.h>
#include <cstddef>

// ---------------- constants ----------------
// B=8, S=1024, T=256, E=256, H=512, Senc=256
// ws layout (float words)
constexpr int OXB0 = 0;                         // (8, 1026, 256) padded ch-last embed(src)
constexpr int OXB1 = OXB0 + 8 * 1026 * 256;     // (8, 514, 256) after conv1+pool
constexpr int OXB2 = OXB1 + 8 * 514 * 256;      // (8, 258, 512) after conv2+pool
constexpr int OENC = OXB2 + 8 * 258 * 512;      // (8, 256, 512) enc
constexpr int OWR1 = OENC + 8 * 256 * 512;      // 768x256   conv1 W^T
constexpr int OWR2 = OWR1 + 768 * 256;          // 768x512   conv2 W^T
constexpr int OWR3 = OWR2 + 768 * 512;          // 1536x512  conv3 W^T
constexpr int OWR0 = OWR3 + 1536 * 512;         // 256x2048  wih0^T
constexpr int OTGT = OWR0 + 256 * 2048;         // 2048x256  embed(tgt), row = t*8+b
constexpr int OXG0 = OTGT + 2048 * 256;         // 2048x2048 xg0 = emb@wih0^T + biases
constexpr int OH0S = OXG0 + 2048 * 2048;        // 257*4096  h0 sequence [t][b][512]
constexpr int OH1S = OH0S + 257 * 4096;         // 257*4096  h1 sequence (dec = t>=1)
constexpr int OCTX = OH1S + 257 * 4096;         // 8*512 ctx per batch
constexpr int OFLG = OCTX + 8 * 512;            // 192*16 ints: per-block flags

constexpr int FSTR = 16;                        // 64B flag stride (one line per producer)

__device__ __forceinline__ float hsum4(const float4& a) { return a.x + a.y + a.z + a.w; }
__device__ __forceinline__ float4 relu4(float4 v, const float4& bv) {
    v.x = fmaxf(v.x + bv.x, 0.f); v.y = fmaxf(v.y + bv.y, 0.f);
    v.z = fmaxf(v.z + bv.z, 0.f); v.w = fmaxf(v.w + bv.w, 0.f); return v;
}
__device__ __forceinline__ float4 max4(const float4& a, const float4& b) {
    float4 r; r.x = fmaxf(a.x, b.x); r.y = fmaxf(a.y, b.y);
    r.z = fmaxf(a.z, b.z); r.w = fmaxf(a.w, b.w); return r;
}
__device__ __forceinline__ float sigmf(float x) { return 1.f / (1.f + expf(-x)); }
__device__ __forceinline__ void fma4(float4& acc, const float4& a, const float4& b) {
    acc.x = fmaf(a.x, b.x, acc.x); acc.y = fmaf(a.y, b.y, acc.y);
    acc.z = fmaf(a.z, b.z, acc.z); acc.w = fmaf(a.w, b.w, acc.w);
}

__device__ __forceinline__ unsigned long long aload64(const float* p) {
    return __hip_atomic_load((const unsigned long long*)p, __ATOMIC_RELAXED,
                             __HIP_MEMORY_SCOPE_AGENT);
}
__device__ __forceinline__ void astore32(float* p, float v) {
    __hip_atomic_store((unsigned int*)p, __float_as_uint(v), __ATOMIC_RELAXED,
                       __HIP_MEMORY_SCOPE_AGENT);
}
__device__ __forceinline__ int aloadi(const int* p) {
    return __hip_atomic_load(p, __ATOMIC_RELAXED, __HIP_MEMORY_SCOPE_AGENT);
}
__device__ __forceinline__ void astorei(int* p, int v) {
    __hip_atomic_store(p, v, __ATOMIC_RELAXED, __HIP_MEMORY_SCOPE_AGENT);
}
__device__ __forceinline__ float2 unpack64(unsigned long long v) {
    float2 f;
    f.x = __uint_as_float((unsigned)v);
    f.y = __uint_as_float((unsigned)(v >> 32));
    return f;
}

// ---------------- init: zero h sequences, flags, conv pad-edge rows ----------------
__global__ void init_kernel(float* __restrict__ ws, int* __restrict__ flags) {
    int idx = blockIdx.x * 256 + threadIdx.x;
    int stride = gridDim.x * 256;
    for (int i = idx; i < 257 * 4096; i += stride) {
        ws[OH0S + i] = 0.f;
        ws[OH1S + i] = 0.f;
    }
    for (int i = idx; i < 192 * FSTR; i += stride) flags[i] = 0;
    for (int i = idx; i < 8 * 2 * 256; i += stride) {
        int b = i >> 9, rr = (i >> 8) & 1, c = i & 255;
        ws[OXB1 + b * 131584 + (rr ? 513 : 0) * 256 + c] = 0.f;
    }
    for (int i = idx; i < 8 * 2 * 512; i += stride) {
        int b = i >> 10, rr = (i >> 9) & 1, c = i & 511;
        ws[OXB2 + b * 132096 + (rr ? 257 : 0) * 512 + c] = 0.f;
    }
}

// ---------------- embedding gathers ----------------
__global__ void embed_src_kernel(const int* __restrict__ src, const float* __restrict__ emb,
                                 float* __restrict__ xb0) {
    int fi = blockIdx.x * 256 + threadIdx.x;          // float4 index, total 8*1026*64
    int e4 = fi & 63;
    int r = fi >> 6;                                  // 0 .. 8*1026-1
    int b = r / 1026;
    int p = r - b * 1026;
    float4 v = make_float4(0.f, 0.f, 0.f, 0.f);
    if (p > 0 && p < 1025) {
        int row = src[b * 1024 + (p - 1)];
        v = *(const float4*)(emb + row * 256 + e4 * 4);
    }
    *(float4*)(xb0 + (size_t)fi * 4) = v;
}

__global__ void gather_tgt_kernel(const int* __restrict__ tgt, const float* __restrict__ emb,
                                  float* __restrict__ et) {
    int fi = blockIdx.x * 256 + threadIdx.x;          // total 2048*64
    int e4 = fi & 63;
    int r = fi >> 6;                                  // m = t*8 + b
    int t = r >> 3, b = r & 7;
    int row = tgt[b * 256 + t];
    *(float4*)(et + (size_t)fi * 4) = *(const float4*)(emb + row * 256 + e4 * 4);
}

// ---------------- weight transposes ----------------
__global__ void tr_conv_kernel(const float* __restrict__ w, float* __restrict__ wr,
                               int Cout, int Cin) {
    int idx = blockIdx.x * 256 + threadIdx.x;
    int co = idx / (Cin * 3);
    int rem = idx - co * Cin * 3;
    int ci = rem / 3;
    int dk = rem - ci * 3;
    wr[(dk * Cin + ci) * Cout + co] = w[idx];
}
__global__ void tr_mat_kernel(const float* __restrict__ w, float* __restrict__ wr,
                              int N, int K) {
    int idx = blockIdx.x * 256 + threadIdx.x;
    int n = idx / K;
    int k = idx - n * K;
    wr[k * N + n] = w[idx];
}

// ---------------- generic tiled GEMM (unchanged, passing) ----------------
__launch_bounds__(256)
__global__ void gemm_kernel(const float* __restrict__ A, int aBS, int RS, int K,
                            const float* __restrict__ Bw, int N,
                            const float* __restrict__ bias, const float* __restrict__ bias2,
                            float* __restrict__ out, int oBS, int mode) {
    __shared__ float As[32 * 68];
    __shared__ float Bs[32 * 64];
    const int tid = threadIdx.x;
    const int tl = tid & 15, tco = tid >> 4;
    const int m0 = blockIdx.x * 64, n0 = blockIdx.y * 64;
    const int b = blockIdx.z;
    const float* Ab = A + (size_t)b * aBS;
    float4 acc0 = make_float4(0, 0, 0, 0), acc1 = acc0, acc2 = acc0, acc3 = acc0;

    for (int k0 = 0; k0 < K; k0 += 32) {
#pragma unroll
        for (int p = 0; p < 2; ++p) {
            int f = p * 256 + tid;
            int row = f >> 3, j4 = f & 7;
            float4 av = *(const float4*)(Ab + (size_t)(m0 + row) * RS + k0 + j4 * 4);
            int kb = j4 * 4;
            As[(kb + 0) * 68 + row] = av.x;
            As[(kb + 1) * 68 + row] = av.y;
            As[(kb + 2) * 68 + row] = av.z;
            As[(kb + 3) * 68 + row] = av.w;
        }
#pragma unroll
        for (int p = 0; p < 2; ++p) {
            int f = p * 256 + tid;
            int kk = f >> 4, j4 = f & 15;
            *(float4*)(&Bs[kk * 64 + j4 * 4]) =
                *(const float4*)(Bw + (size_t)(k0 + kk) * N + n0 + j4 * 4);
        }
        __syncthreads();
#pragma unroll
        for (int kk = 0; kk < 32; ++kk) {
            float4 a4 = *(const float4*)(&As[kk * 68 + tl * 4]);
            float4 b4 = *(const float4*)(&Bs[kk * 64 + tco * 4]);
            acc0.x = fmaf(a4.x, b4.x, acc0.x); acc0.y = fmaf(a4.x, b4.y, acc0.y);
            acc0.z = fmaf(a4.x, b4.z, acc0.z); acc0.w = fmaf(a4.x, b4.w, acc0.w);
            acc1.x = fmaf(a4.y, b4.x, acc1.x); acc1.y = fmaf(a4.y, b4.y, acc1.y);
            acc1.z = fmaf(a4.y, b4.z, acc1.z); acc1.w = fmaf(a4.y, b4.w, acc1.w);
            acc2.x = fmaf(a4.z, b4.x, acc2.x); acc2.y = fmaf(a4.z, b4.y, acc2.y);
            acc2.z = fmaf(a4.z, b4.z, acc2.z); acc2.w = fmaf(a4.z, b4.w, acc2.w);
            acc3.x = fmaf(a4.w, b4.x, acc3.x); acc3.y = fmaf(a4.w, b4.y, acc3.y);
            acc3.z = fmaf(a4.w, b4.z, acc3.z); acc3.w = fmaf(a4.w, b4.w, acc3.w);
        }
        __syncthreads();
    }

    int nb = n0 + tco * 4;
    float4 bv;
    bv.x = bias[nb + 0]; bv.y = bias[nb + 1]; bv.z = bias[nb + 2]; bv.w = bias[nb + 3];
    if (bias2) { bv.x += bias2[nb + 0]; bv.y += bias2[nb + 1]; bv.z += bias2[nb + 2]; bv.w += bias2[nb + 3]; }

    if (mode == 0) {
        float4 v0 = acc0, v1 = acc1, v2 = acc2, v3 = acc3;
        v0.x += bv.x; v0.y += bv.y; v0.z += bv.z; v0.w += bv.w;
        v1.x += bv.x; v1.y += bv.y; v1.z += bv.z; v1.w += bv.w;
        v2.x += bv.x; v2.y += bv.y; v2.z += bv.z; v2.w += bv.w;
        v3.x += bv.x; v3.y += bv.y; v3.z += bv.z; v3.w += bv.w;
        int mr = m0 + tl * 4;
        *(float4*)(out + (size_t)(mr + 0) * N + nb) = v0;
        *(float4*)(out + (size_t)(mr + 1) * N + nb) = v1;
        *(float4*)(out + (size_t)(mr + 2) * N + nb) = v2;
        *(float4*)(out + (size_t)(mr + 3) * N + nb) = v3;
    } else if (mode == 1) {
        float4 v0 = relu4(acc0, bv), v1 = relu4(acc1, bv), v2 = relu4(acc2, bv), v3 = relu4(acc3, bv);
        float4 p0 = max4(v0, v1), p1 = max4(v2, v3);
        int lout = (m0 + tl * 4) >> 1;
        float* ob = out + (size_t)b * oBS + (size_t)(1 + lout) * N + nb;
        *(float4*)ob = p0;
        *(float4*)(ob + N) = p1;
    } else {
        float4 v0 = relu4(acc0, bv), v1 = relu4(acc1, bv), v2 = relu4(acc2, bv), v3 = relu4(acc3, bv);
        int mr = m0 + tl * 4;
        float* ob = out + (size_t)b * oBS + (size_t)mr * N + nb;
        *(float4*)(ob + 0 * N) = v0;
        *(float4*)(ob + 1 * N) = v1;
        *(float4*)(ob + 2 * N) = v2;
        *(float4*)(ob + 3 * N) = v3;
    }
}

// ---------------- persistent 2-layer LSTM (v4.1: distributed flags + tree reduce) ----------------
// 192 blocks x 256 threads, 1 block/CU, W in VGPRs, zero LDS.
// flags[j*FSTR]      : layer0 block j (0..63) stores t+1 after finishing step t
// flags[(64+j)*FSTR] : layer1 block j (0..127) stores t+1 after finishing step t
// Consumers poll producer flags in PARALLEL (one lane per producer), no RMW anywhere.
// Tree reduce: recursive halving over shfl_xor; lane l ends holding value v per the
// lane-bit <-> value-bit pairing noted inline. Owners (8 lanes/group) apply gates.
// v4.1 fix: layer1 reduces 32 values over 64 lanes -> lane bit4 is a SPARE bit; the
// halving levels never exchange it, so each lane pair (l, l^16) holds half-sums of
// the same value. One final s[0] += shfl_xor(s[0],16) completes the reduction.
// (Round-4 failure: this level was missing -> h1 dots were half-summed, absmax 5e-2.)
__launch_bounds__(256, 1)
__global__ void lstm_kernel(const float* __restrict__ xg0,
                            const float* __restrict__ whh0,
                            const float* __restrict__ wih1,
                            const float* __restrict__ whh1,
                            const float* __restrict__ bih1,
                            const float* __restrict__ bhh1,
                            float* __restrict__ h0s, float* __restrict__ h1s,
                            int* __restrict__ flags) {
    const int tid = threadIdx.x;
    const int wg = blockIdx.x;

    if (wg < 64) {
        // ----- layer 0: 8 units (wg0*8 ..+7), K=512 -----
        const int wg0 = wg;
        const int cg = tid >> 6;          // wave: units cg*2+{0,1}
        const int bg = (tid >> 5) & 1;    // batch half
        const int ks = tid & 31;          // K-slice lane; k = q*64 + ks*2 + {0,1}
        float2 W2[4][2][8];
#pragma unroll
        for (int g = 0; g < 4; ++g)
#pragma unroll
            for (int e = 0; e < 2; ++e) {
                const float* wr = whh0 + (size_t)(g * 512 + wg0 * 8 + cg * 2 + e) * 512 + ks * 2;
#pragma unroll
                for (int q = 0; q < 8; ++q)
                    W2[g][e][q] = *(const float2*)(wr + q * 64);
            }
        // value mapping after tree: v = ks = (g<<3)|(e<<2)|bi
        const int vg = ks >> 3, ve = (ks >> 2) & 1, vbi = ks & 3;
        const int vb = bg * 4 + vbi;
        const size_t xgoff = (size_t)vb * 2048 + vg * 512 + wg0 * 8 + cg * 2 + ve;
        // owner lanes ks<8: g=0; same (e,bi) decode
        const int ob = bg * 4 + (ks & 3);
        const int ou = cg * 2 + ((ks >> 2) & 1);
        float cst = 0.f;

        for (int t = 0; t < 256; ++t) {
            float xgv = xg0[(size_t)t * 16384 + xgoff];   // ready data; issues pre-poll
            if (t > 0 && tid < 64) {
                int gd = 1 << 20;
                while (aloadi(&flags[tid * FSTR]) < t && --gd) {}
            }
            __syncthreads();
            // h0[t]: 32 coalesced u64 loads
            unsigned long long hv[4][8];
#pragma unroll
            for (int bi = 0; bi < 4; ++bi) {
                const float* hb = h0s + (size_t)t * 4096 + (bg * 4 + bi) * 512 + ks * 2;
#pragma unroll
                for (int q = 0; q < 8; ++q)
                    hv[bi][q] = aload64(hb + q * 64);
            }
            float2 acc[4][2][4];
#pragma unroll
            for (int g = 0; g < 4; ++g)
#pragma unroll
                for (int e = 0; e < 2; ++e)
#pragma unroll
                    for (int bi = 0; bi < 4; ++bi) acc[g][e][bi] = make_float2(0.f, 0.f);
#pragma unroll
            for (int q = 0; q < 8; ++q)
#pragma unroll
                for (int bi = 0; bi < 4; ++bi) {
                    float2 h2 = unpack64(hv[bi][q]);
#pragma unroll
                    for (int g = 0; g < 4; ++g)
#pragma unroll
                        for (int e = 0; e < 2; ++e) {
                            acc[g][e][bi].x = fmaf(W2[g][e][q].x, h2.x, acc[g][e][bi].x);
                            acc[g][e][bi].y = fmaf(W2[g][e][q].y, h2.y, acc[g][e][bi].y);
                        }
                }
            float s[32];
#pragma unroll
            for (int g = 0; g < 4; ++g)
#pragma unroll
                for (int e = 0; e < 2; ++e)
#pragma unroll
                    for (int bi = 0; bi < 4; ++bi)
                        s[g * 8 + e * 4 + bi] = acc[g][e][bi].x + acc[g][e][bi].y;
            // tree reduce: 5 levels, lane-bit k <-> value-bit k; lane ks ends with value ks
#pragma unroll
            for (int i = 0; i < 16; ++i) {
                float t_ = (ks & 16) ? s[i] : s[i + 16];
                float k_ = (ks & 16) ? s[i + 16] : s[i];
                s[i] = k_ + __shfl_xor(t_, 16);
            }
#pragma unroll
            for (int i = 0; i < 8; ++i) {
                float t_ = (ks & 8) ? s[i] : s[i + 8];
                float k_ = (ks & 8) ? s[i + 8] : s[i];
                s[i] = k_ + __shfl_xor(t_, 8);
            }
#pragma unroll
            for (int i = 0; i < 4; ++i) {
                float t_ = (ks & 4) ? s[i] : s[i + 4];
                float k_ = (ks & 4) ? s[i + 4] : s[i];
                s[i] = k_ + __shfl_xor(t_, 4);
            }
#pragma unroll
            for (int i = 0; i < 2; ++i) {
                float t_ = (ks & 2) ? s[i] : s[i + 2];
                float k_ = (ks & 2) ? s[i + 2] : s[i];
                s[i] = k_ + __shfl_xor(t_, 2);
            }
            {
                float t_ = (ks & 1) ? s[0] : s[1];
                float k_ = (ks & 1) ? s[1] : s[0];
                s[0] = k_ + __shfl_xor(t_, 1);
            }
            float red = s[0] + xgv;               // complete gate value v=ks
            float fgv = __shfl_xor(red, 8);       // v+8  (f gate of my (e,bi))
            float ggv = __shfl_xor(red, 16);      // v+16 (g gate)
            float ogv = __shfl_xor(red, 24);      // v+24 (o gate)
            if (ks < 8) {
                cst = sigmf(fgv) * cst + sigmf(red) * tanhf(ggv);
                float hval = sigmf(ogv) * tanhf(cst);
                astore32(h0s + (size_t)(t + 1) * 4096 + ob * 512 + wg0 * 8 + ou, hval);
            }
            asm volatile("s_waitcnt vmcnt(0)" ::: "memory");
            __syncthreads();
            if (tid == 0) astorei(&flags[wg0 * FSTR], t + 1);
        }
    } else {
        // ----- layer 1: 4 units (wg1*4 ..+3), K=1024 over [h0_{t+1} ; h1_t] -----
        const int wg1 = wg - 64;
        const int w = tid >> 6;
        const int cg = w >> 1, bgv = w & 1;
        const int ks = tid & 63;          // k = q*128 + ks*2 + {0,1}
        float2 W2[4][2][8];
#pragma unroll
        for (int g = 0; g < 4; ++g)
#pragma unroll
            for (int e = 0; e < 2; ++e) {
                const size_t ro = (size_t)(g * 512 + wg1 * 4 + cg * 2 + e) * 512 + ks * 2;
#pragma unroll
                for (int q = 0; q < 4; ++q)
                    W2[g][e][q] = *(const float2*)(wih1 + ro + q * 128);
#pragma unroll
                for (int q = 4; q < 8; ++q)
                    W2[g][e][q] = *(const float2*)(whh1 + ro + (q - 4) * 128);
            }
        // value mapping after tree: v4=ks5, v3=ks3, v2=ks2, v1=ks1, v0=ks0 (ks4 spare)
        const int vg = (((ks >> 5) & 1) << 1) | ((ks >> 3) & 1);
        const int ve = (ks >> 2) & 1, vbi = ks & 3;
        const int rv = vg * 512 + wg1 * 4 + cg * 2 + ve;
        const float biasv = bih1[rv] + bhh1[rv];
        const int ob = bgv * 4 + (ks & 3);
        const int ou = cg * 2 + ((ks >> 2) & 1);
        float cst = 0.f;

        for (int t = 0; t < 256; ++t) {
            if (tid < 64) {
                int gd = 1 << 20;
                while (aloadi(&flags[tid * FSTR]) < t + 1 && --gd) {}
            } else if (tid < 192 && t > 0) {
                int gd = 1 << 20;
                while (aloadi(&flags[tid * FSTR]) < t && --gd) {}   // tid-64+64 = tid
            }
            __syncthreads();
            unsigned long long hv[4][8];
#pragma unroll
            for (int bi = 0; bi < 4; ++bi) {
                const float* h0b = h0s + (size_t)(t + 1) * 4096 + (bgv * 4 + bi) * 512 + ks * 2;
                const float* h1b = h1s + (size_t)t * 4096 + (bgv * 4 + bi) * 512 + ks * 2;
#pragma unroll
                for (int q = 0; q < 4; ++q) hv[bi][q] = aload64(h0b + q * 128);
#pragma unroll
                for (int q = 4; q < 8; ++q) hv[bi][q] = aload64(h1b + (q - 4) * 128);
            }
            float2 acc[4][2][4];
#pragma unroll
            for (int g = 0; g < 4; ++g)
#pragma unroll
                for (int e = 0; e < 2; ++e)
#pragma unroll
                    for (int bi = 0; bi < 4; ++bi) acc[g][e][bi] = make_float2(0.f, 0.f);
#pragma unroll
            for (int q = 0; q < 8; ++q)
#pragma unroll
                for (int bi = 0; bi < 4; ++bi) {
                    float2 h2 = unpack64(hv[bi][q]);
#pragma unroll
                    for (int g = 0; g < 4; ++g)
#pragma unroll
                        for (int e = 0; e < 2; ++e) {
                            acc[g][e][bi].x = fmaf(W2[g][e][q].x, h2.x, acc[g][e][bi].x);
                            acc[g][e][bi].y = fmaf(W2[g][e][q].y, h2.y, acc[g][e][bi].y);
                        }
                }
            float s[32];
#pragma unroll
            for (int g = 0; g < 4; ++g)
#pragma unroll
                for (int e = 0; e < 2; ++e)
#pragma unroll
                    for (int bi = 0; bi < 4; ++bi)
                        s[g * 8 + e * 4 + bi] = acc[g][e][bi].x + acc[g][e][bi].y;
            // level A: lane bit5 <-> value bit4
#pragma unroll
            for (int i = 0; i < 16; ++i) {
                float t_ = (ks & 32) ? s[i] : s[i + 16];
                float k_ = (ks & 32) ? s[i + 16] : s[i];
                s[i] = k_ + __shfl_xor(t_, 32);
            }
#pragma unroll
            for (int i = 0; i < 8; ++i) {
                float t_ = (ks & 8) ? s[i] : s[i + 8];
                float k_ = (ks & 8) ? s[i + 8] : s[i];
                s[i] = k_ + __shfl_xor(t_, 8);
            }
#pragma unroll
            for (int i = 0; i < 4; ++i) {
                float t_ = (ks & 4) ? s[i] : s[i + 4];
                float k_ = (ks & 4) ? s[i + 4] : s[i];
                s[i] = k_ + __shfl_xor(t_, 4);
            }
#pragma unroll
            for (int i = 0; i < 2; ++i) {
                float t_ = (ks & 2) ? s[i] : s[i + 2];
                float k_ = (ks & 2) ? s[i + 2] : s[i];
                s[i] = k_ + __shfl_xor(t_, 2);
            }
            {
                float t_ = (ks & 1) ? s[0] : s[1];
                float k_ = (ks & 1) ? s[1] : s[0];
                s[0] = k_ + __shfl_xor(t_, 1);
            }
            // v4.1 FIX: lane bit4 is spare; (l, l^16) hold half-sums of the same value.
            s[0] += __shfl_xor(s[0], 16);
            float red = s[0] + biasv;
            float fgv = __shfl_xor(red, 8);       // flip v3 -> lane bit3
            float ggv = __shfl_xor(red, 32);      // flip v4 -> lane bit5
            float ogv = __shfl_xor(red, 40);      // flip v4,v3
            if (ks < 8) {
                cst = sigmf(fgv) * cst + sigmf(red) * tanhf(ggv);
                float hval = sigmf(ogv) * tanhf(cst);
                astore32(h1s + (size_t)(t + 1) * 4096 + ob * 512 + wg1 * 4 + ou, hval);
            }
            asm volatile("s_waitcnt vmcnt(0)" ::: "memory");
            __syncthreads();
            if (tid == 0) astorei(&flags[(64 + wg1) * FSTR], t + 1);
        }
    }
}

// ---------------- attention (collapsed): ctx[b] = softmax(enc_p[b,:]) @ enc[b] ----------------
__launch_bounds__(256)
__global__ void attn_kernel(const float* __restrict__ enc, const float* __restrict__ attn_w,
                            float* __restrict__ ctx) {
    __shared__ float aw[512];
    __shared__ float pr[256];
    __shared__ float red[8];
    const int b = blockIdx.x, tid = threadIdx.x;
    if (tid < 128) ((float4*)aw)[tid] = ((const float4*)(attn_w + 512))[tid];
    __syncthreads();
    const float* er = enc + (size_t)(b * 256 + tid) * 512;
    float4 a4 = make_float4(0, 0, 0, 0);
#pragma unroll 8
    for (int i = 0; i < 128; ++i) {
        float4 e4 = *(const float4*)(er + i * 4);
        float4 w4 = *(const float4*)(aw + i * 4);
        fma4(a4, e4, w4);
    }
    float v = hsum4(a4);
    float m = v;
#pragma unroll
    for (int off = 32; off > 0; off >>= 1) m = fmaxf(m, __shfl_xor(m, off));
    if ((tid & 63) == 0) red[tid >> 6] = m;
    __syncthreads();
    if (tid == 0) red[4] = fmaxf(fmaxf(red[0], red[1]), fmaxf(red[2], red[3]));
    __syncthreads();
    float e = expf(v - red[4]);
    pr[tid] = e;
    float s = e;
#pragma unroll
    for (int off = 32; off > 0; off >>= 1) s += __shfl_xor(s, off);
    if ((tid & 63) == 0) red[tid >> 6] = s;
    __syncthreads();
    if (tid == 0) red[5] = red[0] + red[1] + red[2] + red[3];
    __syncthreads();
    float inv = 1.f / red[5];
    for (int hh = tid; hh < 512; hh += 256) {
        float acc = 0.f;
#pragma unroll 8
        for (int s2 = 0; s2 < 256; ++s2)
            acc = fmaf(pr[s2], enc[(size_t)(b * 256 + s2) * 512 + hh], acc);
        ctx[b * 512 + hh] = acc * inv;
    }
}

__global__ void bcast_ctx_kernel(const float* __restrict__ ctx, float* __restrict__ outc) {
    int fi = blockIdx.x * 256 + threadIdx.x;       // f4 idx, total 262144
    int h4 = fi & 127;
    int b = fi >> 15;
    ((float4*)outc)[fi] = ((const float4*)ctx)[b * 128 + h4];
}

// ---------------- output head: (b,t) row -> 10 logits ----------------
__launch_bounds__(256)
__global__ void out_proj_kernel(const float* __restrict__ h1s, const float* __restrict__ ow,
                                const float* __restrict__ ob, float* __restrict__ out) {
    int lane = threadIdx.x & 63;
    int m = blockIdx.x * 4 + (threadIdx.x >> 6);    // 0..2047, m = t*8+b
    int t = m >> 3, b = m & 7;
    const float* dr = h1s + (size_t)(t + 1) * 4096 + b * 512 + lane * 8;
    float4 d0 = *(const float4*)dr;
    float4 d1 = *(const float4*)(dr + 4);
    float acc[10];
#pragma unroll
    for (int v = 0; v < 10; ++v) {
        const float* wr = ow + v * 512 + lane * 8;
        float4 w0 = *(const float4*)wr, w1 = *(const float4*)(wr + 4);
        acc[v] = d0.x * w0.x + d0.y * w0.y + d0.z * w0.z + d0.w * w0.w +
                 d1.x * w1.x + d1.y * w1.y + d1.z * w1.z + d1.w * w1.w;
    }
#pragma unroll
    for (int v = 0; v < 10; ++v)
#pragma unroll
        for (int off = 32; off > 0; off >>= 1) acc[v] += __shfl_xor(acc[v], off);
    if (lane == 0) {
        float* o = out + (size_t)(b * 256 + t) * 10;
#pragma unroll
        for (int v = 0; v < 10; ++v) o[v] = acc[v] + ob[v];
    }
}

// ---------------- launch ----------------
extern "C" void kernel_launch(void* const* d_in, const int* in_sizes, int n_in,
                              void* d_out, int out_size, void* d_ws, size_t ws_size,
                              hipStream_t stream) {
    const int* src = (const int*)d_in[0];
    const int* tgt = (const int*)d_in[1];
    const float* emb = (const float*)d_in[2];
    const float* c1w = (const float*)d_in[3];
    const float* c1b = (const float*)d_in[4];
    const float* c2w = (const float*)d_in[5];
    const float* c2b = (const float*)d_in[6];
    const float* c3w = (const float*)d_in[7];
    const float* c3b = (const float*)d_in[8];
    const float* wih0 = (const float*)d_in[9];
    const float* whh0 = (const float*)d_in[10];
    const float* bih0 = (const float*)d_in[11];
    const float* bhh0 = (const float*)d_in[12];
    const float* wih1 = (const float*)d_in[13];
    const float* whh1 = (const float*)d_in[14];
    const float* bih1 = (const float*)d_in[15];
    const float* bhh1 = (const float*)d_in[16];
    const float* attn_w = (const float*)d_in[17];
    const float* out_w = (const float*)d_in[19];
    const float* out_b = (const float*)d_in[20];

    float* ws = (float*)d_ws;
    float* xb0 = ws + OXB0;
    float* xb1 = ws + OXB1;
    float* xb2 = ws + OXB2;
    float* enc = ws + OENC;
    float* wr1 = ws + OWR1;
    float* wr2 = ws + OWR2;
    float* wr3 = ws + OWR3;
    float* wr0 = ws + OWR0;
    float* etg = ws + OTGT;
    float* xg0 = ws + OXG0;
    float* h0s = ws + OH0S;
    float* h1s = ws + OH1S;
    float* ctx = ws + OCTX;
    int* flags = (int*)(ws + OFLG);
    float* outp = (float*)d_out;

    init_kernel<<<1024, 256, 0, stream>>>(ws, flags);
    embed_src_kernel<<<2052, 256, 0, stream>>>(src, emb, xb0);
    gather_tgt_kernel<<<512, 256, 0, stream>>>(tgt, emb, etg);
    tr_conv_kernel<<<768, 256, 0, stream>>>(c1w, wr1, 256, 256);
    tr_conv_kernel<<<1536, 256, 0, stream>>>(c2w, wr2, 512, 256);
    tr_conv_kernel<<<3072, 256, 0, stream>>>(c3w, wr3, 512, 512);
    tr_mat_kernel<<<2048, 256, 0, stream>>>(wih0, wr0, 2048, 256);

    // xg0 = embtgt @ wih0^T + bih0 + bhh0   (rows ordered t*8+b)
    gemm_kernel<<<dim3(32, 32, 1), 256, 0, stream>>>(etg, 0, 256, 256, wr0, 2048,
                                                     bih0, bhh0, xg0, 0, 0);
    // conv1 + relu + pool: (8,1026,256) -> (8,514,256)
    gemm_kernel<<<dim3(16, 4, 8), 256, 0, stream>>>(xb0, 262656, 256, 768, wr1, 256,
                                                    c1b, nullptr, xb1, 131584, 1);
    // conv2 + relu + pool: (8,514,256) -> (8,258,512)
    gemm_kernel<<<dim3(8, 8, 8), 256, 0, stream>>>(xb1, 131584, 256, 768, wr2, 512,
                                                   c2b, nullptr, xb2, 132096, 1);
    // conv3 + relu: (8,258,512) -> enc (8,256,512)
    gemm_kernel<<<dim3(4, 8, 8), 256, 0, stream>>>(xb2, 132096, 512, 1536, wr3, 512,
                                                   c3b, nullptr, enc, 131072, 2);
    // persistent 2-layer LSTM (no LDS, distributed flags)
    lstm_kernel<<<192, 256, 0, stream>>>(xg0, whh0, wih1, whh1, bih1, bhh1,
                                         h0s, h1s, flags);
    // collapsed attention + context broadcast
    attn_kernel<<<8, 256, 0, stream>>>(enc, attn_w, ctx);
    bcast_ctx_kernel<<<1024, 256, 0, stream>>>(ctx, outp + 20480);
    // output logits
    out_proj_kernel<<<512, 256, 0, stream>>>(h1s, out_w, out_b, outp);
}